// Round 4
// baseline (624.998 us; speedup 1.0000x reference)
//
#include <hip/hip_runtime.h>

#define NN 100000   // nodes
#define NE 1600000  // edges
#define FD 128      // feature dim (4 heads x 32 ch)
#define NB 391      // ceil(NN/256) dst-buckets
#define CAP 4800    // padded bucket capacity (mean 4096, sigma 64 -> +11 sigma)
#define CHUNK 8192  // edges per k_bucket block -> 196 blocks
#define GB 782      // layer-1 gemm tiles (128 rows each)
#define GB2 1563    // fused agg+gemm tiles (64 rows each)
#define PBLK 1563   // pool partial blocks

typedef __attribute__((ext_vector_type(8))) short bf16x8;
typedef __attribute__((ext_vector_type(4))) float f32x4;

union B8 { bf16x8 v; unsigned int u[4]; };

// ---------------- helpers ----------------

__device__ __forceinline__ unsigned short f2bf(float x) {
    unsigned int u = __float_as_uint(x);
    u += 0x7fffu + ((u >> 16) & 1u);   // round-to-nearest-even
    return (unsigned short)(u >> 16);
}

__device__ __forceinline__ unsigned int pkhi(unsigned int ua, unsigned int ub) {
    return __builtin_amdgcn_perm(ub, ua, 0x07060302);
}

__device__ __forceinline__ void split8(const float4& x0, const float4& x1,
                                       bf16x8& hi, bf16x8& lo) {
    float f[8] = {x0.x, x0.y, x0.z, x0.w, x1.x, x1.y, x1.z, x1.w};
    B8 H, L;
#pragma unroll
    for (int i = 0; i < 4; i++) {
        unsigned int ua = __float_as_uint(f[2 * i]);
        unsigned int ub = __float_as_uint(f[2 * i + 1]);
        H.u[i] = pkhi(ua, ub);
        float ra = f[2 * i]     - __uint_as_float(ua & 0xffff0000u);
        float rb = f[2 * i + 1] - __uint_as_float(ub & 0xffff0000u);
        L.u[i] = pkhi(__float_as_uint(ra), __float_as_uint(rb));
    }
    hi = H.v; lo = L.v;
}

// ---------------- W pre-split + gcur zeroing (one dispatch) ----------------

__global__ void k_wsplit3(const float* __restrict__ W1, const float* __restrict__ W2,
                          const float* __restrict__ W3, unsigned short* __restrict__ Wth,
                          unsigned short* __restrict__ Wtl, int* __restrict__ gcur) {
    int gid = blockIdx.x * 256 + threadIdx.x;  // 0..49151
    if (gid < NB) gcur[gid] = 0;
    int w = gid >> 14;
    int tid = gid & 16383;
    const float* W = (w == 0) ? W1 : (w == 1) ? W2 : W3;
    int n = tid >> 7, k = tid & 127;
    float val = W[k * 128 + n];
    unsigned short h = f2bf(val);
    float res = val - __uint_as_float((unsigned int)h << 16);
    Wth[gid] = h;
    Wtl[gid] = f2bf(res);
}

// ---------------- bucket scatter into padded per-bucket slots ----------------
// pairs[b*CAP + slot] = src | (dst&255)<<17

__global__ __launch_bounds__(256) void k_bucket(const int* __restrict__ src,
                                                const int* __restrict__ dst,
                                                int* __restrict__ gcur,
                                                unsigned int* __restrict__ pairs) {
    __shared__ int scnt[NB];
    __shared__ int sbase[NB];
    int t = threadIdx.x;
    for (int i = t; i < NB; i += 256) scnt[i] = 0;
    __syncthreads();
    int e0 = blockIdx.x * CHUNK, e1 = min(e0 + CHUNK, NE);
    for (int i = e0 + t; i < e1; i += 256) atomicAdd(&scnt[dst[i] >> 8], 1);
    __syncthreads();
    for (int i = t; i < NB; i += 256) {
        int c = scnt[i];
        sbase[i] = (c > 0) ? (i * CAP + atomicAdd(&gcur[i], c)) : 0;
        scnt[i] = 0;  // reuse as local cursor
    }
    __syncthreads();
    for (int i = e0 + t; i < e1; i += 256) {
        int d = dst[i];
        int b = d >> 8;
        int r = atomicAdd(&scnt[b], 1);
        pairs[sbase[b] + r] = (unsigned int)src[i] | ((unsigned int)(d & 255) << 17);
    }
}

// ---------------- per-bucket counting sort body ----------------

__device__ void bsort_body(int b, const unsigned int* __restrict__ pairs,
                           const int* __restrict__ gcur, int* __restrict__ off,
                           int* __restrict__ deg, int* __restrict__ ssrc) {
    __shared__ int hcnt[256];
    __shared__ int cur[256];
    int t = threadIdx.x;
    int cnt = gcur[b];
    int estart = b * CAP;
    hcnt[t] = 0;
    __syncthreads();
    for (int i = t; i < cnt; i += 256)
        atomicAdd(&hcnt[(pairs[estart + i] >> 17) & 255], 1);
    __syncthreads();
    int v = hcnt[t];
    cur[t] = v;
    __syncthreads();
    for (int o = 1; o < 256; o <<= 1) {
        int x = (t >= o) ? cur[t - o] : 0;
        __syncthreads();
        cur[t] += x;
        __syncthreads();
    }
    int excl = cur[t] - v;
    int node = (b << 8) + t;
    if (node < NN) {
        off[node] = estart + excl;
        deg[node] = v;
    }
    __syncthreads();
    cur[t] = estart + excl;
    __syncthreads();
    for (int i = t; i < cnt; i += 256) {
        unsigned int p = pairs[estart + i];
        int pos = atomicAdd(&cur[(p >> 17) & 255], 1);
        ssrc[pos] = (int)(p & 0x1ffffu);
    }
}

// ---------------- fused GEMM epilogue (2 row-groups): bf16 features + el/er ----------------

__device__ __forceinline__ void epilogue(f32x4 acc[2][8], int row0, int q, int r, int nrows,
                                         const float* __restrict__ al,
                                         const float* __restrict__ ar,
                                         unsigned short* __restrict__ Fb,
                                         float* __restrict__ el, float* __restrict__ er) {
#pragma unroll
    for (int g = 0; g < 2; g++) {
#pragma unroll
        for (int i = 0; i < 4; i++) {
            int row = row0 + g * 16 + q * 4 + i;
            float elp[4], erp[4];
#pragma unroll
            for (int h = 0; h < 4; h++) { elp[h] = 0.f; erp[h] = 0.f; }
#pragma unroll
            for (int nt = 0; nt < 8; nt++) {
                int h = nt >> 1;
                int c = ((nt & 1) << 4) + r;
                float v = acc[g][nt][i];
                elp[h] = fmaf(v, al[h * 32 + c], elp[h]);
                erp[h] = fmaf(v, ar[h * 32 + c], erp[h]);
            }
#pragma unroll
            for (int o = 1; o < 16; o <<= 1) {
#pragma unroll
                for (int h = 0; h < 4; h++) {
                    elp[h] += __shfl_xor(elp[h], o);
                    erp[h] += __shfl_xor(erp[h], o);
                }
            }
            if (row < nrows) {
#pragma unroll
                for (int nt = 0; nt < 8; nt++)
                    Fb[(size_t)row * FD + nt * 16 + r] = f2bf(acc[g][nt][i]);
                int hh = r & 3;
                float ve = (hh & 2) ? ((hh & 1) ? elp[3] : elp[2]) : ((hh & 1) ? elp[1] : elp[0]);
                float vr = (hh & 2) ? ((hh & 1) ? erp[3] : erp[2]) : ((hh & 1) ? erp[1] : erp[0]);
                if (r < 4) el[row * 4 + hh] = ve;
                else if (r < 8) er[row * 4 + hh] = vr;
            }
        }
    }
}

// ---------------- single-group epilogue (fused agg+gemm waves own 16 rows) ----------------

__device__ __forceinline__ void epilogue1(f32x4 acc[8], int row0, int q, int r, int nrows,
                                          const float* __restrict__ al,
                                          const float* __restrict__ ar,
                                          unsigned short* __restrict__ Fb,
                                          float* __restrict__ el, float* __restrict__ er) {
#pragma unroll
    for (int i = 0; i < 4; i++) {
        int row = row0 + q * 4 + i;
        float elp[4], erp[4];
#pragma unroll
        for (int h = 0; h < 4; h++) { elp[h] = 0.f; erp[h] = 0.f; }
#pragma unroll
        for (int nt = 0; nt < 8; nt++) {
            int h = nt >> 1;
            int c = ((nt & 1) << 4) + r;
            float v = acc[nt][i];
            elp[h] = fmaf(v, al[h * 32 + c], elp[h]);
            erp[h] = fmaf(v, ar[h * 32 + c], erp[h]);
        }
#pragma unroll
        for (int o = 1; o < 16; o <<= 1) {
#pragma unroll
            for (int h = 0; h < 4; h++) {
                elp[h] += __shfl_xor(elp[h], o);
                erp[h] += __shfl_xor(erp[h], o);
            }
        }
        if (row < nrows) {
#pragma unroll
            for (int nt = 0; nt < 8; nt++)
                Fb[(size_t)row * FD + nt * 16 + r] = f2bf(acc[nt][i]);
            int hh = r & 3;
            float ve = (hh & 2) ? ((hh & 1) ? elp[3] : elp[2]) : ((hh & 1) ? elp[1] : elp[0]);
            float vr = (hh & 2) ? ((hh & 1) ? erp[3] : erp[2]) : ((hh & 1) ? erp[1] : erp[0]);
            if (r < 4) el[row * 4 + hh] = ve;
            else if (r < 8) er[row * 4 + hh] = vr;
        }
    }
}

// ---------------- GEMM body (layer 1): A f32, hi/lo split both sides ----------------

__device__ void gemm_f32_body(int bid, const float* __restrict__ A,
                              const unsigned short* __restrict__ Wth,
                              const unsigned short* __restrict__ Wtl,
                              unsigned short* __restrict__ Fb, int nrows,
                              const float* __restrict__ al, const float* __restrict__ ar,
                              float* __restrict__ el, float* __restrict__ er) {
    int t = threadIdx.x;
    int wave = t >> 6, lane = t & 63;
    int r = lane & 15, q = lane >> 4;
    int row0 = bid * 128 + wave * 32;
    int rg0 = row0 + r, rg1 = row0 + 16 + r;

    f32x4 acc[2][8];
#pragma unroll
    for (int g = 0; g < 2; g++)
#pragma unroll
        for (int nt = 0; nt < 8; nt++) acc[g][nt] = (f32x4){0.f, 0.f, 0.f, 0.f};

#pragma unroll
    for (int ks = 0; ks < 4; ks++) {
        int k0 = ks * 32 + q * 8;
        float4 z = make_float4(0.f, 0.f, 0.f, 0.f);
        float4 a0 = z, a1 = z, b0 = z, b1 = z;
        if (rg0 < nrows) {
            const float* pa = A + (size_t)rg0 * FD + k0;
            a0 = *(const float4*)pa;
            a1 = *(const float4*)(pa + 4);
        }
        if (rg1 < nrows) {
            const float* pb = A + (size_t)rg1 * FD + k0;
            b0 = *(const float4*)pb;
            b1 = *(const float4*)(pb + 4);
        }
        bf16x8 ah0, al0, ah1, al1;
        split8(a0, a1, ah0, al0);
        split8(b0, b1, ah1, al1);
#pragma unroll
        for (int nt = 0; nt < 8; nt++) {
            int wo = ((nt * 16 + r) << 7) + k0;
            bf16x8 bh = *(const bf16x8*)(Wth + wo);
            bf16x8 bl = *(const bf16x8*)(Wtl + wo);
            acc[0][nt] = __builtin_amdgcn_mfma_f32_16x16x32_bf16(ah0, bh, acc[0][nt], 0, 0, 0);
            acc[0][nt] = __builtin_amdgcn_mfma_f32_16x16x32_bf16(al0, bh, acc[0][nt], 0, 0, 0);
            acc[0][nt] = __builtin_amdgcn_mfma_f32_16x16x32_bf16(ah0, bl, acc[0][nt], 0, 0, 0);
            acc[1][nt] = __builtin_amdgcn_mfma_f32_16x16x32_bf16(ah1, bh, acc[1][nt], 0, 0, 0);
            acc[1][nt] = __builtin_amdgcn_mfma_f32_16x16x32_bf16(al1, bh, acc[1][nt], 0, 0, 0);
            acc[1][nt] = __builtin_amdgcn_mfma_f32_16x16x32_bf16(ah1, bl, acc[1][nt], 0, 0, 0);
        }
    }
    epilogue(acc, row0, q, r, nrows, al, ar, Fb, el, er);
}

// ---------------- fused dispatch: bsort (blocks 0..NB-1) + layer-1 GEMM (rest) ----------------

__global__ __launch_bounds__(256) void k_sortgemm1(const unsigned int* __restrict__ pairs,
                                                   const int* __restrict__ gcur,
                                                   int* __restrict__ off, int* __restrict__ deg,
                                                   int* __restrict__ ssrc,
                                                   const float* __restrict__ A,
                                                   const unsigned short* __restrict__ Wth,
                                                   const unsigned short* __restrict__ Wtl,
                                                   unsigned short* __restrict__ Fb,
                                                   const float* __restrict__ al,
                                                   const float* __restrict__ ar,
                                                   float* __restrict__ el,
                                                   float* __restrict__ er) {
    int b = blockIdx.x;
    if (b < NB) bsort_body(b, pairs, gcur, off, deg, ssrc);
    else gemm_f32_body(b - NB, A, Wth, Wtl, Fb, NN, al, ar, el, er);
}

// ---------------- wave-wide aggregation of one dst node (relu'd output) ----------------
// All 64 lanes participate. Result: acc8[z] = relu(H[d][8*(lane&15)+z]),
// replicated across the 4 lane-groups (g = lane>>4).

__device__ __forceinline__ void agg_node(int d,
        const unsigned short* __restrict__ Fb,
        const float* __restrict__ el, const float* __restrict__ er,
        const int* __restrict__ off, const int* __restrict__ deg_,
        const int* __restrict__ ssrc, int lane, float acc8[8]) {
#pragma unroll
    for (int z = 0; z < 8; z++) acc8[z] = 0.f;
    int start = off[d];
    int dg = deg_[d];
    if (dg > 0) {
        int h = lane & 3;
        int eloc = lane >> 2;
        int g = lane >> 4;
        int c16 = lane & 15;
        int hsel2 = c16 >> 2;
        float er_h = er[d * 4 + h];
        float s = 0.f;
        for (int base = 0; base < dg; base += 16) {
            int i = base + eloc;
            float a = 0.f;
            int sid = 0;  // invalid lanes -> row 0 with weight 0 (L1-hot, harmless)
            if (i < dg) {
                sid = ssrc[start + i];
                float v = el[sid * 4 + h] + er_h;
                float e = v > 0.f ? v : 0.2f * v;
                a = __expf(e);
            }
            s += a;
#pragma unroll
            for (int k = 0; k < 4; k++) {
                int sl = 16 * k + 4 * g;               // lane holding sid of row 4k+g
                int sid_v = __shfl(sid, sl, 64);
                float av = __shfl(a, sl + hsel2, 64);  // alpha for my head
                uint4 u = *(const uint4*)(Fb + (size_t)sid_v * FD + c16 * 8);
                acc8[0] = fmaf(av, __uint_as_float(u.x << 16),          acc8[0]);
                acc8[1] = fmaf(av, __uint_as_float(u.x & 0xffff0000u),  acc8[1]);
                acc8[2] = fmaf(av, __uint_as_float(u.y << 16),          acc8[2]);
                acc8[3] = fmaf(av, __uint_as_float(u.y & 0xffff0000u),  acc8[3]);
                acc8[4] = fmaf(av, __uint_as_float(u.z << 16),          acc8[4]);
                acc8[5] = fmaf(av, __uint_as_float(u.z & 0xffff0000u),  acc8[5]);
                acc8[6] = fmaf(av, __uint_as_float(u.w << 16),          acc8[6]);
                acc8[7] = fmaf(av, __uint_as_float(u.w & 0xffff0000u),  acc8[7]);
            }
        }
        // merge the 4 row-groups (results become replicated wave-wide)
#pragma unroll
        for (int z = 0; z < 8; z++) {
            acc8[z] += __shfl_xor(acc8[z], 16, 64);
            acc8[z] += __shfl_xor(acc8[z], 32, 64);
        }
        for (int o = 4; o < 64; o <<= 1) s += __shfl_xor(s, o, 64);
        float inv = 1.f / __shfl(s, hsel2, 64);
#pragma unroll
        for (int z = 0; z < 8; z++) acc8[z] *= inv;
    }
#pragma unroll
    for (int z = 0; z < 8; z++) acc8[z] = fmaxf(acc8[z], 0.f);   // relu (all 3 layers)
}

// ---------------- fused agg (layer k) + GEMM (layer k+1), 64 rows/block ----------------
// Wave w aggregates its 16 nodes into LDS (XOR-swizzled bf16 rows) then runs the
// MFMA tile on its own rows — no cross-wave dependency, no barrier. Eliminates
// the Hb global round-trip and the separate k_gemm_bf dispatch.

__global__ __launch_bounds__(256) void k_agggemm(
        const unsigned short* __restrict__ Fb,
        const float* __restrict__ el, const float* __restrict__ er,
        const int* __restrict__ off, const int* __restrict__ deg_,
        const int* __restrict__ ssrc,
        const unsigned short* __restrict__ Wth,
        const unsigned short* __restrict__ Wtl,
        unsigned short* __restrict__ Fbn,
        const float* __restrict__ aln, const float* __restrict__ arn,
        float* __restrict__ eln, float* __restrict__ ern) {
    __shared__ unsigned char lds[64 * 256];   // 64 rows x 128 bf16, swizzled
    int t = threadIdx.x;
    int w = t >> 6, lane = t & 63;
    int c16 = lane & 15, g = lane >> 4;
    int row0 = blockIdx.x * 64 + w * 16;

    for (int n = 0; n < 16; ++n) {
        int d = row0 + n;
        float acc8[8];
        if (d < NN) {
            agg_node(d, Fb, el, er, off, deg_, ssrc, lane, acc8);
        } else {
#pragma unroll
            for (int z = 0; z < 8; z++) acc8[z] = 0.f;
        }
        if (g == 0) {   // 16 lanes write the packed bf16 row (256 B)
            uint4 pk;
            pk.x = ((unsigned int)f2bf(acc8[1]) << 16) | f2bf(acc8[0]);
            pk.y = ((unsigned int)f2bf(acc8[3]) << 16) | f2bf(acc8[2]);
            pk.z = ((unsigned int)f2bf(acc8[5]) << 16) | f2bf(acc8[4]);
            pk.w = ((unsigned int)f2bf(acc8[7]) << 16) | f2bf(acc8[6]);
            int lrow = w * 16 + n;
            int boff = (lrow * 256 + c16 * 16) ^ ((lrow & 7) << 4);
            *(uint4*)(lds + boff) = pk;
        }
    }
    // GEMM phase: wave reads only its own 16 rows (intra-wave LDS ordering).
    int r = c16, q = g;
    f32x4 acc[8];
#pragma unroll
    for (int nt = 0; nt < 8; nt++) acc[nt] = (f32x4){0.f, 0.f, 0.f, 0.f};
    int lrow = w * 16 + r;
#pragma unroll
    for (int ks = 0; ks < 4; ks++) {
        int aoff = (lrow * 256 + ks * 64 + q * 16) ^ ((lrow & 7) << 4);
        bf16x8 a = *(const bf16x8*)(lds + aoff);
        int k0 = ks * 32 + q * 8;
#pragma unroll
        for (int nt = 0; nt < 8; nt++) {
            int wo = ((nt * 16 + r) << 7) + k0;
            bf16x8 bh = *(const bf16x8*)(Wth + wo);
            bf16x8 bl = *(const bf16x8*)(Wtl + wo);
            acc[nt] = __builtin_amdgcn_mfma_f32_16x16x32_bf16(a, bh, acc[nt], 0, 0, 0);
            acc[nt] = __builtin_amdgcn_mfma_f32_16x16x32_bf16(a, bl, acc[nt], 0, 0, 0);
        }
    }
    epilogue1(acc, row0, q, r, NN, aln, arn, Fbn, eln, ern);
}

// ---------------- fused agg (layer 3) + block-local max pool ----------------
// Pool in f32 (monotone wrt the bf16 rounding applied later in k_final).

__global__ __launch_bounds__(256) void k_aggpool(
        const unsigned short* __restrict__ Fb,
        const float* __restrict__ el, const float* __restrict__ er,
        const int* __restrict__ off, const int* __restrict__ deg_,
        const int* __restrict__ ssrc,
        float* __restrict__ partials) {
    __shared__ float wmax[4][128];
    int t = threadIdx.x;
    int w = t >> 6, lane = t & 63;
    int c16 = lane & 15, g = lane >> 4;
    int row0 = blockIdx.x * 64 + w * 16;
    float rm[8];
#pragma unroll
    for (int z = 0; z < 8; z++) rm[z] = 0.f;
    for (int n = 0; n < 16; ++n) {
        int d = row0 + n;
        if (d >= NN) break;
        float acc8[8];
        agg_node(d, Fb, el, er, off, deg_, ssrc, lane, acc8);
#pragma unroll
        for (int z = 0; z < 8; z++) rm[z] = fmaxf(rm[z], acc8[z]);
    }
    if (g == 0) {
#pragma unroll
        for (int z = 0; z < 8; z++) wmax[w][c16 * 8 + z] = rm[z];
    }
    __syncthreads();
    if (t < 128) {
        float m = fmaxf(fmaxf(wmax[0][t], wmax[1][t]), fmaxf(wmax[2][t], wmax[3][t]));
        partials[(size_t)blockIdx.x * 128 + t] = m;
    }
}

// ---------------- final: reduce partials + bf16-round + FC + softmax (1 block) ----------------

__global__ __launch_bounds__(1024) void k_final(const float* __restrict__ partials,
                                                const float* __restrict__ Wfc,
                                                const float* __restrict__ bfc,
                                                float* __restrict__ outp) {
    __shared__ float red[1024];
    int t = threadIdx.x;
    int c = t & 127;             // channel
    int slice = t >> 7;          // 8 row-slices
    const int RPS = (PBLK + 7) / 8;  // 196
    float m = 0.f;
    int i0 = slice * RPS;
    for (int k = 0; k < RPS; ++k) {
        int i = i0 + k;
        if (i < PBLK) m = fmaxf(m, partials[(size_t)i * 128 + c]);
    }
    red[t] = m;
    __syncthreads();
    if (t < 128) {
        float v = red[t];
#pragma unroll
        for (int s = 1; s < 8; ++s) v = fmaxf(v, red[s * 128 + t]);
        // bf16-round the pooled value (matches the previous Hb-bf16 numerics)
        red[t] = __uint_as_float((unsigned int)f2bf(v) << 16);
    }
    __syncthreads();
    if (t < 64) {
        int j = t & 7;
        int kk = t >> 3;
        float partial = 0.f;
        for (int k = kk * 16; k < kk * 16 + 16; ++k) partial += red[k] * Wfc[k * 8 + j];
        for (int o = 8; o < 64; o <<= 1) partial += __shfl_xor(partial, o);
        float logit = partial + bfc[j];
        float mxl = logit;
        for (int o = 1; o < 8; o <<= 1) mxl = fmaxf(mxl, __shfl_xor(mxl, o));
        float ex = __expf(logit - mxl);
        float sm = ex;
        for (int o = 1; o < 8; o <<= 1) sm += __shfl_xor(sm, o);
        if (t < 8) outp[t] = ex / sm;
    }
}

// ---------------- launch ----------------

extern "C" void kernel_launch(void* const* d_in, const int* in_sizes, int n_in,
                              void* d_out, int out_size, void* d_ws, size_t ws_size,
                              hipStream_t stream) {
    const float* x   = (const float*)d_in[0];
    const int*   src = (const int*)d_in[1];
    const int*   dst = (const int*)d_in[2];
    const float* W1  = (const float*)d_in[3];
    const float* al1 = (const float*)d_in[4];
    const float* ar1 = (const float*)d_in[5];
    const float* W2  = (const float*)d_in[6];
    const float* al2 = (const float*)d_in[7];
    const float* ar2 = (const float*)d_in[8];
    const float* W3  = (const float*)d_in[9];
    const float* al3 = (const float*)d_in[10];
    const float* ar3 = (const float*)d_in[11];
    const float* Wfc = (const float*)d_in[12];
    const float* bfc = (const float*)d_in[13];
    float* out = (float*)d_out;

    char* p = (char*)d_ws;
    auto alloc = [&](size_t bytes) {
        char* r = p;
        p += (bytes + 255) & ~(size_t)255;
        return r;
    };
    unsigned short* Fb_a = (unsigned short*)alloc((size_t)NN * FD * 2);
    unsigned short* Fb_b = (unsigned short*)alloc((size_t)NN * FD * 2);
    float* el_a   = (float*)alloc((size_t)NN * 4 * 4);
    float* er_a   = (float*)alloc((size_t)NN * 4 * 4);
    int*   off    = (int*)alloc((size_t)NN * 4);
    int*   deg    = (int*)alloc((size_t)NN * 4);
    int*   ssrc   = (int*)alloc((size_t)NB * CAP * 4);
    unsigned int* pairs = (unsigned int*)alloc((size_t)NB * CAP * 4);
    int*   gcur   = (int*)alloc((size_t)NB * 4);
    float* partials = (float*)alloc((size_t)PBLK * 128 * 4);
    unsigned short* Wth = (unsigned short*)alloc(3 * 16384 * 2);
    unsigned short* Wtl = (unsigned short*)alloc(3 * 16384 * 2);
    // pairs (7.5 MB) is dead after k_sortgemm1's bsort -> overlay layer-B el/er (3.2 MB)
    float* el_b = (float*)pairs;
    float* er_b = (float*)pairs + (size_t)NN * 4;

    const int BB = (NE + CHUNK - 1) / CHUNK;  // 196

    k_wsplit3<<<192, 256, 0, stream>>>(W1, W2, W3, Wth, Wtl, gcur);
    k_bucket<<<BB, 256, 0, stream>>>(src, dst, gcur, pairs);

    // bsort + layer-1 GEMM fused (independent work) -> Fb_a, el_a, er_a
    k_sortgemm1<<<NB + GB, 256, 0, stream>>>(pairs, gcur, off, deg, ssrc,
                                             x, Wth, Wtl, Fb_a, al1, ar1, el_a, er_a);
    // agg layer-1 + GEMM layer-2 -> Fb_b, el_b, er_b
    k_agggemm<<<GB2, 256, 0, stream>>>(Fb_a, el_a, er_a, off, deg, ssrc,
                                       Wth + 16384, Wtl + 16384, Fb_b, al2, ar2, el_b, er_b);
    // agg layer-2 + GEMM layer-3 -> Fb_a, el_a, er_a
    k_agggemm<<<GB2, 256, 0, stream>>>(Fb_b, el_b, er_b, off, deg, ssrc,
                                       Wth + 32768, Wtl + 32768, Fb_a, al3, ar3, el_a, er_a);
    // agg layer-3 + block-local max pool
    k_aggpool<<<PBLK, 256, 0, stream>>>(Fb_a, el_a, er_a, off, deg, ssrc, partials);
    k_final<<<1, 1024, 0, stream>>>(partials, Wfc, bfc, out);
}

// Round 5
// 535.461 us; speedup vs baseline: 1.1672x; 1.1672x over previous
//
#include <hip/hip_runtime.h>

#define NN 100000   // nodes
#define NE 1600000  // edges
#define FD 128      // feature dim (4 heads x 32 ch)
#define NB 391      // ceil(NN/256) dst-buckets
#define CAP 4800    // padded bucket capacity (mean 4096, sigma 64 -> +11 sigma)
#define CHUNK 8192  // edges per k_bucket block -> 196 blocks
#define GB 782      // layer-1 gemm tiles (128 rows each)
#define NPB 16      // nodes per fused agg+gemm block (1 node per wave!)
#define FBLK 6250   // ceil(NN/NPB)
#define PBLK2 128   // second-stage pool rows

typedef __attribute__((ext_vector_type(8))) short bf16x8;
typedef __attribute__((ext_vector_type(4))) float f32x4;

union B8 { bf16x8 v; unsigned int u[4]; };

// ---------------- helpers ----------------

__device__ __forceinline__ unsigned short f2bf(float x) {
    unsigned int u = __float_as_uint(x);
    u += 0x7fffu + ((u >> 16) & 1u);   // round-to-nearest-even
    return (unsigned short)(u >> 16);
}

__device__ __forceinline__ unsigned int pkhi(unsigned int ua, unsigned int ub) {
    return __builtin_amdgcn_perm(ub, ua, 0x07060302);
}

__device__ __forceinline__ void split8(const float4& x0, const float4& x1,
                                       bf16x8& hi, bf16x8& lo) {
    float f[8] = {x0.x, x0.y, x0.z, x0.w, x1.x, x1.y, x1.z, x1.w};
    B8 H, L;
#pragma unroll
    for (int i = 0; i < 4; i++) {
        unsigned int ua = __float_as_uint(f[2 * i]);
        unsigned int ub = __float_as_uint(f[2 * i + 1]);
        H.u[i] = pkhi(ua, ub);
        float ra = f[2 * i]     - __uint_as_float(ua & 0xffff0000u);
        float rb = f[2 * i + 1] - __uint_as_float(ub & 0xffff0000u);
        L.u[i] = pkhi(__float_as_uint(ra), __float_as_uint(rb));
    }
    hi = H.v; lo = L.v;
}

// ---------------- W pre-split + gcur zeroing (one dispatch) ----------------

__global__ void k_wsplit3(const float* __restrict__ W1, const float* __restrict__ W2,
                          const float* __restrict__ W3, unsigned short* __restrict__ Wth,
                          unsigned short* __restrict__ Wtl, int* __restrict__ gcur) {
    int gid = blockIdx.x * 256 + threadIdx.x;  // 0..49151
    if (gid < NB) gcur[gid] = 0;
    int w = gid >> 14;
    int tid = gid & 16383;
    const float* W = (w == 0) ? W1 : (w == 1) ? W2 : W3;
    int n = tid >> 7, k = tid & 127;
    float val = W[k * 128 + n];
    unsigned short h = f2bf(val);
    float res = val - __uint_as_float((unsigned int)h << 16);
    Wth[gid] = h;
    Wtl[gid] = f2bf(res);
}

// ---------------- bucket scatter into padded per-bucket slots ----------------
// pairs[b*CAP + slot] = src | (dst&255)<<17

__global__ __launch_bounds__(256) void k_bucket(const int* __restrict__ src,
                                                const int* __restrict__ dst,
                                                int* __restrict__ gcur,
                                                unsigned int* __restrict__ pairs) {
    __shared__ int scnt[NB];
    __shared__ int sbase[NB];
    int t = threadIdx.x;
    for (int i = t; i < NB; i += 256) scnt[i] = 0;
    __syncthreads();
    int e0 = blockIdx.x * CHUNK, e1 = min(e0 + CHUNK, NE);
    for (int i = e0 + t; i < e1; i += 256) atomicAdd(&scnt[dst[i] >> 8], 1);
    __syncthreads();
    for (int i = t; i < NB; i += 256) {
        int c = scnt[i];
        sbase[i] = (c > 0) ? (i * CAP + atomicAdd(&gcur[i], c)) : 0;
        scnt[i] = 0;  // reuse as local cursor
    }
    __syncthreads();
    for (int i = e0 + t; i < e1; i += 256) {
        int d = dst[i];
        int b = d >> 8;
        int r = atomicAdd(&scnt[b], 1);
        pairs[sbase[b] + r] = (unsigned int)src[i] | ((unsigned int)(d & 255) << 17);
    }
}

// ---------------- per-bucket counting sort body ----------------

__device__ void bsort_body(int b, const unsigned int* __restrict__ pairs,
                           const int* __restrict__ gcur, int* __restrict__ off,
                           int* __restrict__ deg, int* __restrict__ ssrc) {
    __shared__ int hcnt[256];
    __shared__ int cur[256];
    int t = threadIdx.x;
    int cnt = gcur[b];
    int estart = b * CAP;
    hcnt[t] = 0;
    __syncthreads();
    for (int i = t; i < cnt; i += 256)
        atomicAdd(&hcnt[(pairs[estart + i] >> 17) & 255], 1);
    __syncthreads();
    int v = hcnt[t];
    cur[t] = v;
    __syncthreads();
    for (int o = 1; o < 256; o <<= 1) {
        int x = (t >= o) ? cur[t - o] : 0;
        __syncthreads();
        cur[t] += x;
        __syncthreads();
    }
    int excl = cur[t] - v;
    int node = (b << 8) + t;
    if (node < NN) {
        off[node] = estart + excl;
        deg[node] = v;
    }
    __syncthreads();
    cur[t] = estart + excl;
    __syncthreads();
    for (int i = t; i < cnt; i += 256) {
        unsigned int p = pairs[estart + i];
        int pos = atomicAdd(&cur[(p >> 17) & 255], 1);
        ssrc[pos] = (int)(p & 0x1ffffu);
    }
}

// ---------------- fused GEMM epilogue (2 row-groups): bf16 features + el/er ----------------

__device__ __forceinline__ void epilogue(f32x4 acc[2][8], int row0, int q, int r, int nrows,
                                         const float* __restrict__ al,
                                         const float* __restrict__ ar,
                                         unsigned short* __restrict__ Fb,
                                         float* __restrict__ el, float* __restrict__ er) {
#pragma unroll
    for (int g = 0; g < 2; g++) {
#pragma unroll
        for (int i = 0; i < 4; i++) {
            int row = row0 + g * 16 + q * 4 + i;
            float elp[4], erp[4];
#pragma unroll
            for (int h = 0; h < 4; h++) { elp[h] = 0.f; erp[h] = 0.f; }
#pragma unroll
            for (int nt = 0; nt < 8; nt++) {
                int h = nt >> 1;
                int c = ((nt & 1) << 4) + r;
                float v = acc[g][nt][i];
                elp[h] = fmaf(v, al[h * 32 + c], elp[h]);
                erp[h] = fmaf(v, ar[h * 32 + c], erp[h]);
            }
#pragma unroll
            for (int o = 1; o < 16; o <<= 1) {
#pragma unroll
                for (int h = 0; h < 4; h++) {
                    elp[h] += __shfl_xor(elp[h], o);
                    erp[h] += __shfl_xor(erp[h], o);
                }
            }
            if (row < nrows) {
#pragma unroll
                for (int nt = 0; nt < 8; nt++)
                    Fb[(size_t)row * FD + nt * 16 + r] = f2bf(acc[g][nt][i]);
                int hh = r & 3;
                float ve = (hh & 2) ? ((hh & 1) ? elp[3] : elp[2]) : ((hh & 1) ? elp[1] : elp[0]);
                float vr = (hh & 2) ? ((hh & 1) ? erp[3] : erp[2]) : ((hh & 1) ? erp[1] : erp[0]);
                if (r < 4) el[row * 4 + hh] = ve;
                else if (r < 8) er[row * 4 + hh] = vr;
            }
        }
    }
}

// ---------------- GEMM body (layer 1): A f32, hi/lo split both sides ----------------

__device__ void gemm_f32_body(int bid, const float* __restrict__ A,
                              const unsigned short* __restrict__ Wth,
                              const unsigned short* __restrict__ Wtl,
                              unsigned short* __restrict__ Fb, int nrows,
                              const float* __restrict__ al, const float* __restrict__ ar,
                              float* __restrict__ el, float* __restrict__ er) {
    int t = threadIdx.x;
    int wave = t >> 6, lane = t & 63;
    int r = lane & 15, q = lane >> 4;
    int row0 = bid * 128 + wave * 32;
    int rg0 = row0 + r, rg1 = row0 + 16 + r;

    f32x4 acc[2][8];
#pragma unroll
    for (int g = 0; g < 2; g++)
#pragma unroll
        for (int nt = 0; nt < 8; nt++) acc[g][nt] = (f32x4){0.f, 0.f, 0.f, 0.f};

#pragma unroll
    for (int ks = 0; ks < 4; ks++) {
        int k0 = ks * 32 + q * 8;
        float4 z = make_float4(0.f, 0.f, 0.f, 0.f);
        float4 a0 = z, a1 = z, b0 = z, b1 = z;
        if (rg0 < nrows) {
            const float* pa = A + (size_t)rg0 * FD + k0;
            a0 = *(const float4*)pa;
            a1 = *(const float4*)(pa + 4);
        }
        if (rg1 < nrows) {
            const float* pb = A + (size_t)rg1 * FD + k0;
            b0 = *(const float4*)pb;
            b1 = *(const float4*)(pb + 4);
        }
        bf16x8 ah0, al0, ah1, al1;
        split8(a0, a1, ah0, al0);
        split8(b0, b1, ah1, al1);
#pragma unroll
        for (int nt = 0; nt < 8; nt++) {
            int wo = ((nt * 16 + r) << 7) + k0;
            bf16x8 bh = *(const bf16x8*)(Wth + wo);
            bf16x8 bl = *(const bf16x8*)(Wtl + wo);
            acc[0][nt] = __builtin_amdgcn_mfma_f32_16x16x32_bf16(ah0, bh, acc[0][nt], 0, 0, 0);
            acc[0][nt] = __builtin_amdgcn_mfma_f32_16x16x32_bf16(al0, bh, acc[0][nt], 0, 0, 0);
            acc[0][nt] = __builtin_amdgcn_mfma_f32_16x16x32_bf16(ah0, bl, acc[0][nt], 0, 0, 0);
            acc[1][nt] = __builtin_amdgcn_mfma_f32_16x16x32_bf16(ah1, bh, acc[1][nt], 0, 0, 0);
            acc[1][nt] = __builtin_amdgcn_mfma_f32_16x16x32_bf16(al1, bh, acc[1][nt], 0, 0, 0);
            acc[1][nt] = __builtin_amdgcn_mfma_f32_16x16x32_bf16(ah1, bl, acc[1][nt], 0, 0, 0);
        }
    }
    epilogue(acc, row0, q, r, nrows, al, ar, Fb, el, er);
}

// ---------------- fused dispatch: bsort (blocks 0..NB-1) + layer-1 GEMM (rest) ----------------

__global__ __launch_bounds__(256) void k_sortgemm1(const unsigned int* __restrict__ pairs,
                                                   const int* __restrict__ gcur,
                                                   int* __restrict__ off, int* __restrict__ deg,
                                                   int* __restrict__ ssrc,
                                                   const float* __restrict__ A,
                                                   const unsigned short* __restrict__ Wth,
                                                   const unsigned short* __restrict__ Wtl,
                                                   unsigned short* __restrict__ Fb,
                                                   const float* __restrict__ al,
                                                   const float* __restrict__ ar,
                                                   float* __restrict__ el,
                                                   float* __restrict__ er) {
    int b = blockIdx.x;
    if (b < NB) bsort_body(b, pairs, gcur, off, deg, ssrc);
    else gemm_f32_body(b - NB, A, Wth, Wtl, Fb, NN, al, ar, el, er);
}

// ---------------- wave-wide aggregation of one dst node (relu'd output) ----------------
// All 64 lanes participate. Result: acc8[z] = relu(H[d][8*(lane&15)+z]),
// replicated across the 4 lane-groups (g = lane>>4).

__device__ __forceinline__ void agg_node(int d,
        const unsigned short* __restrict__ Fb,
        const float* __restrict__ el, const float* __restrict__ er,
        const int* __restrict__ off, const int* __restrict__ deg_,
        const int* __restrict__ ssrc, int lane, float acc8[8]) {
#pragma unroll
    for (int z = 0; z < 8; z++) acc8[z] = 0.f;
    int start = off[d];
    int dg = deg_[d];
    if (dg > 0) {
        int h = lane & 3;
        int eloc = lane >> 2;
        int g = lane >> 4;
        int c16 = lane & 15;
        int hsel2 = c16 >> 2;
        float er_h = er[d * 4 + h];
        float s = 0.f;
        for (int base = 0; base < dg; base += 16) {
            int i = base + eloc;
            float a = 0.f;
            int sid = 0;  // invalid lanes -> row 0 with weight 0 (L1-hot, harmless)
            if (i < dg) {
                sid = ssrc[start + i];
                float v = el[sid * 4 + h] + er_h;
                float e = v > 0.f ? v : 0.2f * v;
                a = __expf(e);
            }
            s += a;
#pragma unroll
            for (int k = 0; k < 4; k++) {
                int sl = 16 * k + 4 * g;               // lane holding sid of row 4k+g
                int sid_v = __shfl(sid, sl, 64);
                float av = __shfl(a, sl + hsel2, 64);  // alpha for my head
                uint4 u = *(const uint4*)(Fb + (size_t)sid_v * FD + c16 * 8);
                acc8[0] = fmaf(av, __uint_as_float(u.x << 16),          acc8[0]);
                acc8[1] = fmaf(av, __uint_as_float(u.x & 0xffff0000u),  acc8[1]);
                acc8[2] = fmaf(av, __uint_as_float(u.y << 16),          acc8[2]);
                acc8[3] = fmaf(av, __uint_as_float(u.y & 0xffff0000u),  acc8[3]);
                acc8[4] = fmaf(av, __uint_as_float(u.z << 16),          acc8[4]);
                acc8[5] = fmaf(av, __uint_as_float(u.z & 0xffff0000u),  acc8[5]);
                acc8[6] = fmaf(av, __uint_as_float(u.w << 16),          acc8[6]);
                acc8[7] = fmaf(av, __uint_as_float(u.w & 0xffff0000u),  acc8[7]);
            }
        }
        // merge the 4 row-groups (results become replicated wave-wide)
#pragma unroll
        for (int z = 0; z < 8; z++) {
            acc8[z] += __shfl_xor(acc8[z], 16, 64);
            acc8[z] += __shfl_xor(acc8[z], 32, 64);
        }
        for (int o = 4; o < 64; o <<= 1) s += __shfl_xor(s, o, 64);
        float inv = 1.f / __shfl(s, hsel2, 64);
#pragma unroll
        for (int z = 0; z < 8; z++) acc8[z] *= inv;
    }
#pragma unroll
    for (int z = 0; z < 8; z++) acc8[z] = fmaxf(acc8[z], 0.f);   // relu (all 3 layers)
}

// ---------------- fused agg (layer k) + GEMM (layer k+1) ----------------
// 1024 threads = 16 waves; ONE NODE PER WAVE (full 100K-wave agg TLP).
// Each wave writes its relu'd bf16 row into swizzled LDS; after one barrier,
// waves 0..3 each run the 16-row x 32-col GEMM for head w (16 MFMAs) and the
// per-head epilogue. Waves 4..15 exit. Hb round-trip eliminated.

__global__ __launch_bounds__(1024, 8) void k_agggemm2(
        const unsigned short* __restrict__ Fb,
        const float* __restrict__ el, const float* __restrict__ er,
        const int* __restrict__ off, const int* __restrict__ deg_,
        const int* __restrict__ ssrc,
        const unsigned short* __restrict__ Wth,
        const unsigned short* __restrict__ Wtl,
        unsigned short* __restrict__ Fbn,
        const float* __restrict__ aln, const float* __restrict__ arn,
        float* __restrict__ eln, float* __restrict__ ern) {
    __shared__ unsigned char lds[NPB * 256];   // 16 rows x 128 bf16, swizzled
    int t = threadIdx.x;
    int w = t >> 6, lane = t & 63;
    int c16 = lane & 15, g = lane >> 4;
    int row0 = blockIdx.x * NPB;
    int d = row0 + w;

    float acc8[8];
    if (d < NN) {
        agg_node(d, Fb, el, er, off, deg_, ssrc, lane, acc8);
    } else {
#pragma unroll
        for (int z = 0; z < 8; z++) acc8[z] = 0.f;
    }
    if (g == 0) {   // 16 lanes write the packed bf16 row (256 B)
        uint4 pk;
        pk.x = ((unsigned int)f2bf(acc8[1]) << 16) | f2bf(acc8[0]);
        pk.y = ((unsigned int)f2bf(acc8[3]) << 16) | f2bf(acc8[2]);
        pk.z = ((unsigned int)f2bf(acc8[5]) << 16) | f2bf(acc8[4]);
        pk.w = ((unsigned int)f2bf(acc8[7]) << 16) | f2bf(acc8[6]);
        int boff = (w * 256 + c16 * 16) ^ ((w & 7) << 4);
        *(uint4*)(lds + boff) = pk;
    }
    __syncthreads();
    if (w >= 4) return;

    // GEMM phase: wave w computes head w (cols 32w..32w+31) for the 16 rows.
    int r = c16, q = g;
    f32x4 acc[2];
    acc[0] = (f32x4){0.f, 0.f, 0.f, 0.f};
    acc[1] = (f32x4){0.f, 0.f, 0.f, 0.f};
#pragma unroll
    for (int ks = 0; ks < 4; ks++) {
        int aoff = (r * 256 + ks * 64 + q * 16) ^ ((r & 7) << 4);
        bf16x8 a = *(const bf16x8*)(lds + aoff);
        int k0 = ks * 32 + q * 8;
#pragma unroll
        for (int nl = 0; nl < 2; nl++) {
            int nt = 2 * w + nl;
            int wo = ((nt * 16 + r) << 7) + k0;
            bf16x8 bh = *(const bf16x8*)(Wth + wo);
            bf16x8 bl = *(const bf16x8*)(Wtl + wo);
            acc[nl] = __builtin_amdgcn_mfma_f32_16x16x32_bf16(a, bh, acc[nl], 0, 0, 0);
            acc[nl] = __builtin_amdgcn_mfma_f32_16x16x32_bf16(a, bl, acc[nl], 0, 0, 0);
        }
    }
    // per-head epilogue: bf16 features + el/er for head w
#pragma unroll
    for (int i = 0; i < 4; i++) {
        int row = row0 + q * 4 + i;
        float elp = 0.f, erp = 0.f;
#pragma unroll
        for (int nl = 0; nl < 2; nl++) {
            int c = (nl << 4) + r;           // channel within head w (0..31)
            float v = acc[nl][i];
            elp = fmaf(v, aln[w * 32 + c], elp);
            erp = fmaf(v, arn[w * 32 + c], erp);
        }
#pragma unroll
        for (int o = 1; o < 16; o <<= 1) {
            elp += __shfl_xor(elp, o);
            erp += __shfl_xor(erp, o);
        }
        if (row < NN) {
#pragma unroll
            for (int nl = 0; nl < 2; nl++)
                Fbn[(size_t)row * FD + (2 * w + nl) * 16 + r] = f2bf(acc[nl][i]);
            if (r == 0) {
                eln[row * 4 + w] = elp;
                ern[row * 4 + w] = erp;
            }
        }
    }
}

// ---------------- fused agg (layer 3) + block-local max pool ----------------
// Same 1-node-per-wave shape; block max over its 16 rows -> partials[FBLK][128].

__global__ __launch_bounds__(1024, 8) void k_aggpool2(
        const unsigned short* __restrict__ Fb,
        const float* __restrict__ el, const float* __restrict__ er,
        const int* __restrict__ off, const int* __restrict__ deg_,
        const int* __restrict__ ssrc,
        float* __restrict__ partials) {
    __shared__ float wmax[NPB][128];
    int t = threadIdx.x;
    int w = t >> 6, lane = t & 63;
    int c16 = lane & 15, g = lane >> 4;
    int d = blockIdx.x * NPB + w;
    float acc8[8];
    if (d < NN) {
        agg_node(d, Fb, el, er, off, deg_, ssrc, lane, acc8);
    } else {
#pragma unroll
        for (int z = 0; z < 8; z++) acc8[z] = 0.f;
    }
    if (g == 0) {
#pragma unroll
        for (int z = 0; z < 8; z++) wmax[w][c16 * 8 + z] = acc8[z];
    }
    __syncthreads();
    if (t < 128) {
        float m = 0.f;
#pragma unroll
        for (int i = 0; i < NPB; i++) m = fmaxf(m, wmax[i][t]);
        partials[(size_t)blockIdx.x * 128 + t] = m;
    }
}

// ---------------- pool reduce: FBLK partial rows -> PBLK2 rows ----------------

__global__ __launch_bounds__(128) void k_poolred(const float* __restrict__ partials,
                                                 float* __restrict__ partials2) {
    int c = threadIdx.x;         // channel 0..127
    int b = blockIdx.x;          // 0..127
    float m = 0.f;
    for (int r = b; r < FBLK; r += PBLK2)
        m = fmaxf(m, partials[(size_t)r * 128 + c]);
    partials2[(size_t)b * 128 + c] = m;
}

// ---------------- final: reduce partials2 + bf16-round + FC + softmax (1 block) ----------------

__global__ __launch_bounds__(1024) void k_final(const float* __restrict__ partials2,
                                                const float* __restrict__ Wfc,
                                                const float* __restrict__ bfc,
                                                float* __restrict__ outp) {
    __shared__ float red[1024];
    int t = threadIdx.x;
    int c = t & 127;             // channel
    int slice = t >> 7;          // 8 row-slices of 16 rows each
    float m = 0.f;
    int i0 = slice * (PBLK2 / 8);
#pragma unroll
    for (int k = 0; k < PBLK2 / 8; ++k)
        m = fmaxf(m, partials2[(size_t)(i0 + k) * 128 + c]);
    red[t] = m;
    __syncthreads();
    if (t < 128) {
        float v = red[t];
#pragma unroll
        for (int s = 1; s < 8; ++s) v = fmaxf(v, red[s * 128 + t]);
        // bf16-round the pooled value (matches the Hb-bf16 numerics of the ref path)
        red[t] = __uint_as_float((unsigned int)f2bf(v) << 16);
    }
    __syncthreads();
    if (t < 64) {
        int j = t & 7;
        int kk = t >> 3;
        float partial = 0.f;
        for (int k = kk * 16; k < kk * 16 + 16; ++k) partial += red[k] * Wfc[k * 8 + j];
        for (int o = 8; o < 64; o <<= 1) partial += __shfl_xor(partial, o);
        float logit = partial + bfc[j];
        float mxl = logit;
        for (int o = 1; o < 8; o <<= 1) mxl = fmaxf(mxl, __shfl_xor(mxl, o));
        float ex = __expf(logit - mxl);
        float sm = ex;
        for (int o = 1; o < 8; o <<= 1) sm += __shfl_xor(sm, o);
        if (t < 8) outp[t] = ex / sm;
    }
}

// ---------------- launch ----------------

extern "C" void kernel_launch(void* const* d_in, const int* in_sizes, int n_in,
                              void* d_out, int out_size, void* d_ws, size_t ws_size,
                              hipStream_t stream) {
    const float* x   = (const float*)d_in[0];
    const int*   src = (const int*)d_in[1];
    const int*   dst = (const int*)d_in[2];
    const float* W1  = (const float*)d_in[3];
    const float* al1 = (const float*)d_in[4];
    const float* ar1 = (const float*)d_in[5];
    const float* W2  = (const float*)d_in[6];
    const float* al2 = (const float*)d_in[7];
    const float* ar2 = (const float*)d_in[8];
    const float* W3  = (const float*)d_in[9];
    const float* al3 = (const float*)d_in[10];
    const float* ar3 = (const float*)d_in[11];
    const float* Wfc = (const float*)d_in[12];
    const float* bfc = (const float*)d_in[13];
    float* out = (float*)d_out;

    char* p = (char*)d_ws;
    auto alloc = [&](size_t bytes) {
        char* r = p;
        p += (bytes + 255) & ~(size_t)255;
        return r;
    };
    unsigned short* Fb_a = (unsigned short*)alloc((size_t)NN * FD * 2);
    unsigned short* Fb_b = (unsigned short*)alloc((size_t)NN * FD * 2);
    float* el_a   = (float*)alloc((size_t)NN * 4 * 4);
    float* er_a   = (float*)alloc((size_t)NN * 4 * 4);
    int*   off    = (int*)alloc((size_t)NN * 4);
    int*   deg    = (int*)alloc((size_t)NN * 4);
    int*   ssrc   = (int*)alloc((size_t)NB * CAP * 4);
    unsigned int* pairs = (unsigned int*)alloc((size_t)NB * CAP * 4);
    int*   gcur   = (int*)alloc((size_t)NB * 4);
    float* partials  = (float*)alloc((size_t)FBLK * 128 * 4);   // 3.2 MB
    float* partials2 = (float*)alloc((size_t)PBLK2 * 128 * 4);  // 64 KB
    unsigned short* Wth = (unsigned short*)alloc(3 * 16384 * 2);
    unsigned short* Wtl = (unsigned short*)alloc(3 * 16384 * 2);
    // pairs (7.5 MB) is dead after k_sortgemm1's bsort -> overlay layer-B el/er (3.2 MB)
    float* el_b = (float*)pairs;
    float* er_b = (float*)pairs + (size_t)NN * 4;

    const int BB = (NE + CHUNK - 1) / CHUNK;  // 196

    k_wsplit3<<<192, 256, 0, stream>>>(W1, W2, W3, Wth, Wtl, gcur);
    k_bucket<<<BB, 256, 0, stream>>>(src, dst, gcur, pairs);

    // bsort + layer-1 GEMM fused (independent work) -> Fb_a, el_a, er_a
    k_sortgemm1<<<NB + GB, 256, 0, stream>>>(pairs, gcur, off, deg, ssrc,
                                             x, Wth, Wtl, Fb_a, al1, ar1, el_a, er_a);
    // agg layer-1 + GEMM layer-2 -> Fb_b, el_b, er_b
    k_agggemm2<<<FBLK, 1024, 0, stream>>>(Fb_a, el_a, er_a, off, deg, ssrc,
                                          Wth + 16384, Wtl + 16384, Fb_b, al2, ar2, el_b, er_b);
    // agg layer-2 + GEMM layer-3 -> Fb_a, el_a, er_a
    k_agggemm2<<<FBLK, 1024, 0, stream>>>(Fb_b, el_b, er_b, off, deg, ssrc,
                                          Wth + 32768, Wtl + 32768, Fb_a, al3, ar3, el_a, er_a);
    // agg layer-3 + block-local max pool
    k_aggpool2<<<FBLK, 1024, 0, stream>>>(Fb_a, el_a, er_a, off, deg, ssrc, partials);
    k_poolred<<<PBLK2, 128, 0, stream>>>(partials, partials2);
    k_final<<<1, 1024, 0, stream>>>(partials2, Wfc, bfc, out);
}

// Round 6
// 504.467 us; speedup vs baseline: 1.2389x; 1.0614x over previous
//
#include <hip/hip_runtime.h>

#define NN 100000   // nodes
#define NE 1600000  // edges
#define FD 128      // feature dim (4 heads x 32 ch); fp8 row = 128 B
#define NB 391      // ceil(NN/256) dst-buckets
#define CAP 4800    // padded bucket capacity (mean 4096, sigma 64 -> +11 sigma)
#define CHUNK 8192  // edges per k_bucket block -> 196 blocks
#define GB 782      // layer-1 gemm tiles (128 rows each)
#define NPB 16      // nodes per fused agg+gemm block (1 node per wave)
#define FBLK 6250   // ceil(NN/NPB)
#define PBLK2 128   // second-stage pool rows

typedef __attribute__((ext_vector_type(8))) short bf16x8;
typedef __attribute__((ext_vector_type(4))) float f32x4;

union B8 { bf16x8 v; unsigned int u[4]; };

// ---------------- helpers ----------------

__device__ __forceinline__ unsigned short f2bf(float x) {
    unsigned int u = __float_as_uint(x);
    u += 0x7fffu + ((u >> 16) & 1u);   // round-to-nearest-even
    return (unsigned short)(u >> 16);
}

__device__ __forceinline__ unsigned char f2fp8(float x) {
    // low byte of packed fp8 conversion (RNE, saturating)
    return (unsigned char)__builtin_amdgcn_cvt_pk_fp8_f32(x, 0.f, 0u, false);
}

__device__ __forceinline__ unsigned int pkhi(unsigned int ua, unsigned int ub) {
    return __builtin_amdgcn_perm(ub, ua, 0x07060302);
}

__device__ __forceinline__ void split8(const float4& x0, const float4& x1,
                                       bf16x8& hi, bf16x8& lo) {
    float f[8] = {x0.x, x0.y, x0.z, x0.w, x1.x, x1.y, x1.z, x1.w};
    B8 H, L;
#pragma unroll
    for (int i = 0; i < 4; i++) {
        unsigned int ua = __float_as_uint(f[2 * i]);
        unsigned int ub = __float_as_uint(f[2 * i + 1]);
        H.u[i] = pkhi(ua, ub);
        float ra = f[2 * i]     - __uint_as_float(ua & 0xffff0000u);
        float rb = f[2 * i + 1] - __uint_as_float(ub & 0xffff0000u);
        L.u[i] = pkhi(__float_as_uint(ra), __float_as_uint(rb));
    }
    hi = H.v; lo = L.v;
}

// ---------------- W pre-split + gcur zeroing (one dispatch) ----------------

__global__ void k_wsplit3(const float* __restrict__ W1, const float* __restrict__ W2,
                          const float* __restrict__ W3, unsigned short* __restrict__ Wth,
                          unsigned short* __restrict__ Wtl, int* __restrict__ gcur) {
    int gid = blockIdx.x * 256 + threadIdx.x;  // 0..49151
    if (gid < NB) gcur[gid] = 0;
    int w = gid >> 14;
    int tid = gid & 16383;
    const float* W = (w == 0) ? W1 : (w == 1) ? W2 : W3;
    int n = tid >> 7, k = tid & 127;
    float val = W[k * 128 + n];
    unsigned short h = f2bf(val);
    float res = val - __uint_as_float((unsigned int)h << 16);
    Wth[gid] = h;
    Wtl[gid] = f2bf(res);
}

// ---------------- bucket scatter into padded per-bucket slots ----------------
// pairs[b*CAP + slot] = src | (dst&255)<<17

__global__ __launch_bounds__(256) void k_bucket(const int* __restrict__ src,
                                                const int* __restrict__ dst,
                                                int* __restrict__ gcur,
                                                unsigned int* __restrict__ pairs) {
    __shared__ int scnt[NB];
    __shared__ int sbase[NB];
    int t = threadIdx.x;
    for (int i = t; i < NB; i += 256) scnt[i] = 0;
    __syncthreads();
    int e0 = blockIdx.x * CHUNK, e1 = min(e0 + CHUNK, NE);
    for (int i = e0 + t; i < e1; i += 256) atomicAdd(&scnt[dst[i] >> 8], 1);
    __syncthreads();
    for (int i = t; i < NB; i += 256) {
        int c = scnt[i];
        sbase[i] = (c > 0) ? (i * CAP + atomicAdd(&gcur[i], c)) : 0;
        scnt[i] = 0;  // reuse as local cursor
    }
    __syncthreads();
    for (int i = e0 + t; i < e1; i += 256) {
        int d = dst[i];
        int b = d >> 8;
        int r = atomicAdd(&scnt[b], 1);
        pairs[sbase[b] + r] = (unsigned int)src[i] | ((unsigned int)(d & 255) << 17);
    }
}

// ---------------- per-bucket counting sort body ----------------

__device__ void bsort_body(int b, const unsigned int* __restrict__ pairs,
                           const int* __restrict__ gcur, int* __restrict__ off,
                           int* __restrict__ deg, int* __restrict__ ssrc) {
    __shared__ int hcnt[256];
    __shared__ int cur[256];
    int t = threadIdx.x;
    int cnt = gcur[b];
    int estart = b * CAP;
    hcnt[t] = 0;
    __syncthreads();
    for (int i = t; i < cnt; i += 256)
        atomicAdd(&hcnt[(pairs[estart + i] >> 17) & 255], 1);
    __syncthreads();
    int v = hcnt[t];
    cur[t] = v;
    __syncthreads();
    for (int o = 1; o < 256; o <<= 1) {
        int x = (t >= o) ? cur[t - o] : 0;
        __syncthreads();
        cur[t] += x;
        __syncthreads();
    }
    int excl = cur[t] - v;
    int node = (b << 8) + t;
    if (node < NN) {
        off[node] = estart + excl;
        deg[node] = v;
    }
    __syncthreads();
    cur[t] = estart + excl;
    __syncthreads();
    for (int i = t; i < cnt; i += 256) {
        unsigned int p = pairs[estart + i];
        int pos = atomicAdd(&cur[(p >> 17) & 255], 1);
        ssrc[pos] = (int)(p & 0x1ffffu);
    }
}

// ---------------- fused GEMM epilogue (2 row-groups): fp8 features + el/er ----------------
// Features staged as fp8 bytes in wave-private LDS, then copied out as uint4
// (coalesced) — avoids 2-byte scattered global stores (partial-line RMW).

__device__ __forceinline__ void epilogue(f32x4 acc[2][8], int row0, int q, int r, int nrows,
                                         const float* __restrict__ al,
                                         const float* __restrict__ ar,
                                         unsigned char* __restrict__ FbG,
                                         float* __restrict__ el, float* __restrict__ er,
                                         unsigned char* __restrict__ sg8, int lane) {
#pragma unroll
    for (int g = 0; g < 2; g++) {
#pragma unroll
        for (int i = 0; i < 4; i++) {
            int row_l = g * 16 + q * 4 + i;
            int row = row0 + row_l;
            float elp[4], erp[4];
#pragma unroll
            for (int h = 0; h < 4; h++) { elp[h] = 0.f; erp[h] = 0.f; }
#pragma unroll
            for (int nt = 0; nt < 8; nt++) {
                int h = nt >> 1;
                int c = ((nt & 1) << 4) + r;
                float v = acc[g][nt][i];
                elp[h] = fmaf(v, al[h * 32 + c], elp[h]);
                erp[h] = fmaf(v, ar[h * 32 + c], erp[h]);
            }
#pragma unroll
            for (int o = 1; o < 16; o <<= 1) {
#pragma unroll
                for (int h = 0; h < 4; h++) {
                    elp[h] += __shfl_xor(elp[h], o);
                    erp[h] += __shfl_xor(erp[h], o);
                }
            }
#pragma unroll
            for (int nt = 0; nt < 8; nt++)
                sg8[row_l * 128 + nt * 16 + r] = f2fp8(acc[g][nt][i]);
            if (row < nrows) {
                int hh = r & 3;
                float ve = (hh & 2) ? ((hh & 1) ? elp[3] : elp[2]) : ((hh & 1) ? elp[1] : elp[0]);
                float vr = (hh & 2) ? ((hh & 1) ? erp[3] : erp[2]) : ((hh & 1) ? erp[1] : erp[0]);
                if (r < 4) el[row * 4 + hh] = ve;
                else if (r < 8) er[row * 4 + hh] = vr;
            }
        }
    }
    // copy out the wave's 32 rows (4 KB), wave-private -> no barrier needed
#pragma unroll
    for (int it = 0; it < 4; it++) {
        int off = it * 1024 + lane * 16;
        int row = row0 + (off >> 7);
        uint4 v = *(const uint4*)(sg8 + off);
        if (row < nrows) *(uint4*)(FbG + (size_t)row * FD + (off & 127)) = v;
    }
}

// ---------------- GEMM body (layer 1): A f32, hi/lo split both sides ----------------

__device__ void gemm_f32_body(int bid, const float* __restrict__ A,
                              const unsigned short* __restrict__ Wth,
                              const unsigned short* __restrict__ Wtl,
                              unsigned char* __restrict__ Fb, int nrows,
                              const float* __restrict__ al, const float* __restrict__ ar,
                              float* __restrict__ el, float* __restrict__ er) {
    __shared__ unsigned char sg8[4][4096];   // per-wave fp8 staging (32 rows x 128 B)
    int t = threadIdx.x;
    int wave = t >> 6, lane = t & 63;
    int r = lane & 15, q = lane >> 4;
    int row0 = bid * 128 + wave * 32;
    int rg0 = row0 + r, rg1 = row0 + 16 + r;

    f32x4 acc[2][8];
#pragma unroll
    for (int g = 0; g < 2; g++)
#pragma unroll
        for (int nt = 0; nt < 8; nt++) acc[g][nt] = (f32x4){0.f, 0.f, 0.f, 0.f};

#pragma unroll
    for (int ks = 0; ks < 4; ks++) {
        int k0 = ks * 32 + q * 8;
        float4 z = make_float4(0.f, 0.f, 0.f, 0.f);
        float4 a0 = z, a1 = z, b0 = z, b1 = z;
        if (rg0 < nrows) {
            const float* pa = A + (size_t)rg0 * FD + k0;
            a0 = *(const float4*)pa;
            a1 = *(const float4*)(pa + 4);
        }
        if (rg1 < nrows) {
            const float* pb = A + (size_t)rg1 * FD + k0;
            b0 = *(const float4*)pb;
            b1 = *(const float4*)(pb + 4);
        }
        bf16x8 ah0, al0, ah1, al1;
        split8(a0, a1, ah0, al0);
        split8(b0, b1, ah1, al1);
#pragma unroll
        for (int nt = 0; nt < 8; nt++) {
            int wo = ((nt * 16 + r) << 7) + k0;
            bf16x8 bh = *(const bf16x8*)(Wth + wo);
            bf16x8 bl = *(const bf16x8*)(Wtl + wo);
            acc[0][nt] = __builtin_amdgcn_mfma_f32_16x16x32_bf16(ah0, bh, acc[0][nt], 0, 0, 0);
            acc[0][nt] = __builtin_amdgcn_mfma_f32_16x16x32_bf16(al0, bh, acc[0][nt], 0, 0, 0);
            acc[0][nt] = __builtin_amdgcn_mfma_f32_16x16x32_bf16(ah0, bl, acc[0][nt], 0, 0, 0);
            acc[1][nt] = __builtin_amdgcn_mfma_f32_16x16x32_bf16(ah1, bh, acc[1][nt], 0, 0, 0);
            acc[1][nt] = __builtin_amdgcn_mfma_f32_16x16x32_bf16(al1, bh, acc[1][nt], 0, 0, 0);
            acc[1][nt] = __builtin_amdgcn_mfma_f32_16x16x32_bf16(ah1, bl, acc[1][nt], 0, 0, 0);
        }
    }
    epilogue(acc, row0, q, r, nrows, al, ar, Fb, el, er, sg8[wave], lane);
}

// ---------------- fused dispatch: bsort (blocks 0..NB-1) + layer-1 GEMM (rest) ----------------

__global__ __launch_bounds__(256) void k_sortgemm1(const unsigned int* __restrict__ pairs,
                                                   const int* __restrict__ gcur,
                                                   int* __restrict__ off, int* __restrict__ deg,
                                                   int* __restrict__ ssrc,
                                                   const float* __restrict__ A,
                                                   const unsigned short* __restrict__ Wth,
                                                   const unsigned short* __restrict__ Wtl,
                                                   unsigned char* __restrict__ Fb,
                                                   const float* __restrict__ al,
                                                   const float* __restrict__ ar,
                                                   float* __restrict__ el,
                                                   float* __restrict__ er) {
    int b = blockIdx.x;
    if (b < NB) bsort_body(b, pairs, gcur, off, deg, ssrc);
    else gemm_f32_body(b - NB, A, Wth, Wtl, Fb, NN, al, ar, el, er);
}

// ---------------- wave-wide aggregation of one dst node (relu'd output) ----------------
// Features gathered as fp8 (8 B/lane), dequant via v_cvt_pk_f32_fp8.
// Result: acc8[z] = relu(H[d][8*(lane&15)+z]), replicated across 4 lane-groups.

__device__ __forceinline__ void agg_node(int d,
        const unsigned char* __restrict__ Fb,
        const float* __restrict__ el, const float* __restrict__ er,
        const int* __restrict__ off, const int* __restrict__ deg_,
        const int* __restrict__ ssrc, int lane, float acc8[8]) {
#pragma unroll
    for (int z = 0; z < 8; z++) acc8[z] = 0.f;
    int start = off[d];
    int dg = deg_[d];
    if (dg > 0) {
        int h = lane & 3;
        int eloc = lane >> 2;
        int g = lane >> 4;
        int c16 = lane & 15;
        int hsel2 = c16 >> 2;
        float er_h = er[d * 4 + h];
        float s = 0.f;
        for (int base = 0; base < dg; base += 16) {
            int i = base + eloc;
            float a = 0.f;
            int sid = 0;  // invalid lanes -> row 0 with weight 0 (L1-hot, harmless)
            if (i < dg) {
                sid = ssrc[start + i];
                float v = el[sid * 4 + h] + er_h;
                float e = v > 0.f ? v : 0.2f * v;
                a = __expf(e);
            }
            s += a;
#pragma unroll
            for (int k = 0; k < 4; k++) {
                int sl = 16 * k + 4 * g;               // lane holding sid of row 4k+g
                int sid_v = __shfl(sid, sl, 64);
                float av = __shfl(a, sl + hsel2, 64);  // alpha for my head
                uint2 u = *(const uint2*)(Fb + (size_t)sid_v * FD + c16 * 8);
                {
                    auto p = __builtin_amdgcn_cvt_pk_f32_fp8(u.x, false);
                    acc8[0] = fmaf(av, p[0], acc8[0]);
                    acc8[1] = fmaf(av, p[1], acc8[1]);
                }
                {
                    auto p = __builtin_amdgcn_cvt_pk_f32_fp8(u.x, true);
                    acc8[2] = fmaf(av, p[0], acc8[2]);
                    acc8[3] = fmaf(av, p[1], acc8[3]);
                }
                {
                    auto p = __builtin_amdgcn_cvt_pk_f32_fp8(u.y, false);
                    acc8[4] = fmaf(av, p[0], acc8[4]);
                    acc8[5] = fmaf(av, p[1], acc8[5]);
                }
                {
                    auto p = __builtin_amdgcn_cvt_pk_f32_fp8(u.y, true);
                    acc8[6] = fmaf(av, p[0], acc8[6]);
                    acc8[7] = fmaf(av, p[1], acc8[7]);
                }
            }
        }
        // merge the 4 row-groups (results become replicated wave-wide)
#pragma unroll
        for (int z = 0; z < 8; z++) {
            acc8[z] += __shfl_xor(acc8[z], 16, 64);
            acc8[z] += __shfl_xor(acc8[z], 32, 64);
        }
        for (int o = 4; o < 64; o <<= 1) s += __shfl_xor(s, o, 64);
        float inv = 1.f / __shfl(s, hsel2, 64);
#pragma unroll
        for (int z = 0; z < 8; z++) acc8[z] *= inv;
    }
#pragma unroll
    for (int z = 0; z < 8; z++) acc8[z] = fmaxf(acc8[z], 0.f);   // relu (all 3 layers)
}

// ---------------- fused agg (layer k) + GEMM (layer k+1) ----------------
// 1024 threads = 16 waves; ONE NODE PER WAVE. Aggregated rows -> bf16 LDS (A),
// barrier, waves 0..3 each compute one head's GEMM + el/er, write fp8 features
// to LDS, barrier, coalesced uint4 copy-out of Fbn (no scattered 2B stores).

__global__ __launch_bounds__(1024, 8) void k_agggemm2(
        const unsigned char* __restrict__ Fb,
        const float* __restrict__ el, const float* __restrict__ er,
        const int* __restrict__ off, const int* __restrict__ deg_,
        const int* __restrict__ ssrc,
        const unsigned short* __restrict__ Wth,
        const unsigned short* __restrict__ Wtl,
        unsigned char* __restrict__ Fbn,
        const float* __restrict__ aln, const float* __restrict__ arn,
        float* __restrict__ eln, float* __restrict__ ern) {
    __shared__ unsigned char lds[NPB * 256];   // 16 rows x 128 bf16 (A), swizzled
    __shared__ unsigned char lds8[NPB * 128];  // 16 rows x 128 fp8 (output staging)
    int t = threadIdx.x;
    int w = t >> 6, lane = t & 63;
    int c16 = lane & 15, g = lane >> 4;
    int row0 = blockIdx.x * NPB;
    int d = row0 + w;

    float acc8[8];
    if (d < NN) {
        agg_node(d, Fb, el, er, off, deg_, ssrc, lane, acc8);
    } else {
#pragma unroll
        for (int z = 0; z < 8; z++) acc8[z] = 0.f;
    }
    if (g == 0) {   // 16 lanes write the packed bf16 row (256 B)
        uint4 pk;
        pk.x = ((unsigned int)f2bf(acc8[1]) << 16) | f2bf(acc8[0]);
        pk.y = ((unsigned int)f2bf(acc8[3]) << 16) | f2bf(acc8[2]);
        pk.z = ((unsigned int)f2bf(acc8[5]) << 16) | f2bf(acc8[4]);
        pk.w = ((unsigned int)f2bf(acc8[7]) << 16) | f2bf(acc8[6]);
        int boff = (w * 256 + c16 * 16) ^ ((w & 7) << 4);
        *(uint4*)(lds + boff) = pk;
    }
    __syncthreads();

    if (w < 4) {
        // GEMM phase: wave w computes head w (cols 32w..32w+31) for the 16 rows.
        int r = c16, q = g;
        f32x4 acc[2];
        acc[0] = (f32x4){0.f, 0.f, 0.f, 0.f};
        acc[1] = (f32x4){0.f, 0.f, 0.f, 0.f};
#pragma unroll
        for (int ks = 0; ks < 4; ks++) {
            int aoff = (r * 256 + ks * 64 + q * 16) ^ ((r & 7) << 4);
            bf16x8 a = *(const bf16x8*)(lds + aoff);
            int k0 = ks * 32 + q * 8;
#pragma unroll
            for (int nl = 0; nl < 2; nl++) {
                int nt = 2 * w + nl;
                int wo = ((nt * 16 + r) << 7) + k0;
                bf16x8 bh = *(const bf16x8*)(Wth + wo);
                bf16x8 bl = *(const bf16x8*)(Wtl + wo);
                acc[nl] = __builtin_amdgcn_mfma_f32_16x16x32_bf16(a, bh, acc[nl], 0, 0, 0);
                acc[nl] = __builtin_amdgcn_mfma_f32_16x16x32_bf16(a, bl, acc[nl], 0, 0, 0);
            }
        }
        // per-head epilogue: fp8 features to LDS + el/er for head w
#pragma unroll
        for (int i = 0; i < 4; i++) {
            int row_l = q * 4 + i;
            int row = row0 + row_l;
            float elp = 0.f, erp = 0.f;
#pragma unroll
            for (int nl = 0; nl < 2; nl++) {
                int c = (nl << 4) + r;           // channel within head w (0..31)
                float v = acc[nl][i];
                elp = fmaf(v, aln[w * 32 + c], elp);
                erp = fmaf(v, arn[w * 32 + c], erp);
            }
#pragma unroll
            for (int o = 1; o < 16; o <<= 1) {
                elp += __shfl_xor(elp, o);
                erp += __shfl_xor(erp, o);
            }
#pragma unroll
            for (int nl = 0; nl < 2; nl++)
                lds8[row_l * 128 + (2 * w + nl) * 16 + r] = f2fp8(acc[nl][i]);
            if (row < NN && r == 0) {
                eln[row * 4 + w] = elp;
                ern[row * 4 + w] = erp;
            }
        }
    }
    __syncthreads();
    // coalesced copy-out: 16 rows x 128 B = 2 KB = 128 uint4 chunks
    if (t < 128) {
        int row = row0 + (t >> 3);
        uint4 v = *(const uint4*)(lds8 + t * 16);
        if (row < NN) *(uint4*)(Fbn + (size_t)row * FD + (t & 7) * 16) = v;
    }
}

// ---------------- fused agg (layer 3) + block-local max pool ----------------
// Same 1-node-per-wave shape; block max over its 16 rows -> partials[FBLK][128].

__global__ __launch_bounds__(1024, 8) void k_aggpool2(
        const unsigned char* __restrict__ Fb,
        const float* __restrict__ el, const float* __restrict__ er,
        const int* __restrict__ off, const int* __restrict__ deg_,
        const int* __restrict__ ssrc,
        float* __restrict__ partials) {
    __shared__ float wmax[NPB][128];
    int t = threadIdx.x;
    int w = t >> 6, lane = t & 63;
    int c16 = lane & 15, g = lane >> 4;
    int d = blockIdx.x * NPB + w;
    float acc8[8];
    if (d < NN) {
        agg_node(d, Fb, el, er, off, deg_, ssrc, lane, acc8);
    } else {
#pragma unroll
        for (int z = 0; z < 8; z++) acc8[z] = 0.f;
    }
    if (g == 0) {
#pragma unroll
        for (int z = 0; z < 8; z++) wmax[w][c16 * 8 + z] = acc8[z];
    }
    __syncthreads();
    if (t < 128) {
        float m = 0.f;
#pragma unroll
        for (int i = 0; i < NPB; i++) m = fmaxf(m, wmax[i][t]);
        partials[(size_t)blockIdx.x * 128 + t] = m;
    }
}

// ---------------- pool reduce: FBLK partial rows -> PBLK2 rows ----------------

__global__ __launch_bounds__(128) void k_poolred(const float* __restrict__ partials,
                                                 float* __restrict__ partials2) {
    int c = threadIdx.x;         // channel 0..127
    int b = blockIdx.x;          // 0..127
    float m = 0.f;
    for (int r = b; r < FBLK; r += PBLK2)
        m = fmaxf(m, partials[(size_t)r * 128 + c]);
    partials2[(size_t)b * 128 + c] = m;
}

// ---------------- final: reduce partials2 + bf16-round + FC + softmax (1 block) ----------------

__global__ __launch_bounds__(1024) void k_final(const float* __restrict__ partials2,
                                                const float* __restrict__ Wfc,
                                                const float* __restrict__ bfc,
                                                float* __restrict__ outp) {
    __shared__ float red[1024];
    int t = threadIdx.x;
    int c = t & 127;             // channel
    int slice = t >> 7;          // 8 row-slices of 16 rows each
    float m = 0.f;
    int i0 = slice * (PBLK2 / 8);
#pragma unroll
    for (int k = 0; k < PBLK2 / 8; ++k)
        m = fmaxf(m, partials2[(size_t)(i0 + k) * 128 + c]);
    red[t] = m;
    __syncthreads();
    if (t < 128) {
        float v = red[t];
#pragma unroll
        for (int s = 1; s < 8; ++s) v = fmaxf(v, red[s * 128 + t]);
        // bf16-round the pooled value (matches the prior pipeline numerics)
        red[t] = __uint_as_float((unsigned int)f2bf(v) << 16);
    }
    __syncthreads();
    if (t < 64) {
        int j = t & 7;
        int kk = t >> 3;
        float partial = 0.f;
        for (int k = kk * 16; k < kk * 16 + 16; ++k) partial += red[k] * Wfc[k * 8 + j];
        for (int o = 8; o < 64; o <<= 1) partial += __shfl_xor(partial, o);
        float logit = partial + bfc[j];
        float mxl = logit;
        for (int o = 1; o < 8; o <<= 1) mxl = fmaxf(mxl, __shfl_xor(mxl, o));
        float ex = __expf(logit - mxl);
        float sm = ex;
        for (int o = 1; o < 8; o <<= 1) sm += __shfl_xor(sm, o);
        if (t < 8) outp[t] = ex / sm;
    }
}

// ---------------- launch ----------------

extern "C" void kernel_launch(void* const* d_in, const int* in_sizes, int n_in,
                              void* d_out, int out_size, void* d_ws, size_t ws_size,
                              hipStream_t stream) {
    const float* x   = (const float*)d_in[0];
    const int*   src = (const int*)d_in[1];
    const int*   dst = (const int*)d_in[2];
    const float* W1  = (const float*)d_in[3];
    const float* al1 = (const float*)d_in[4];
    const float* ar1 = (const float*)d_in[5];
    const float* W2  = (const float*)d_in[6];
    const float* al2 = (const float*)d_in[7];
    const float* ar2 = (const float*)d_in[8];
    const float* W3  = (const float*)d_in[9];
    const float* al3 = (const float*)d_in[10];
    const float* ar3 = (const float*)d_in[11];
    const float* Wfc = (const float*)d_in[12];
    const float* bfc = (const float*)d_in[13];
    float* out = (float*)d_out;

    char* p = (char*)d_ws;
    auto alloc = [&](size_t bytes) {
        char* r = p;
        p += (bytes + 255) & ~(size_t)255;
        return r;
    };
    unsigned char* Fb_a = (unsigned char*)alloc((size_t)NN * FD);   // fp8 features
    unsigned char* Fb_b = (unsigned char*)alloc((size_t)NN * FD);
    float* el_a   = (float*)alloc((size_t)NN * 4 * 4);
    float* er_a   = (float*)alloc((size_t)NN * 4 * 4);
    int*   off    = (int*)alloc((size_t)NN * 4);
    int*   deg    = (int*)alloc((size_t)NN * 4);
    int*   ssrc   = (int*)alloc((size_t)NB * CAP * 4);
    unsigned int* pairs = (unsigned int*)alloc((size_t)NB * CAP * 4);
    int*   gcur   = (int*)alloc((size_t)NB * 4);
    float* partials  = (float*)alloc((size_t)FBLK * 128 * 4);   // 3.2 MB
    float* partials2 = (float*)alloc((size_t)PBLK2 * 128 * 4);  // 64 KB
    unsigned short* Wth = (unsigned short*)alloc(3 * 16384 * 2);
    unsigned short* Wtl = (unsigned short*)alloc(3 * 16384 * 2);
    // pairs (7.5 MB) is dead after k_sortgemm1's bsort -> overlay layer-B el/er (3.2 MB)
    float* el_b = (float*)pairs;
    float* er_b = (float*)pairs + (size_t)NN * 4;

    const int BB = (NE + CHUNK - 1) / CHUNK;  // 196

    k_wsplit3<<<192, 256, 0, stream>>>(W1, W2, W3, Wth, Wtl, gcur);
    k_bucket<<<BB, 256, 0, stream>>>(src, dst, gcur, pairs);

    // bsort + layer-1 GEMM fused (independent work) -> Fb_a, el_a, er_a
    k_sortgemm1<<<NB + GB, 256, 0, stream>>>(pairs, gcur, off, deg, ssrc,
                                             x, Wth, Wtl, Fb_a, al1, ar1, el_a, er_a);
    // agg layer-1 + GEMM layer-2 -> Fb_b, el_b, er_b
    k_agggemm2<<<FBLK, 1024, 0, stream>>>(Fb_a, el_a, er_a, off, deg, ssrc,
                                          Wth + 16384, Wtl + 16384, Fb_b, al2, ar2, el_b, er_b);
    // agg layer-2 + GEMM layer-3 -> Fb_a, el_a, er_a
    k_agggemm2<<<FBLK, 1024, 0, stream>>>(Fb_b, el_b, er_b, off, deg, ssrc,
                                          Wth + 32768, Wtl + 32768, Fb_a, al3, ar3, el_a, er_a);
    // agg layer-3 + block-local max pool
    k_aggpool2<<<FBLK, 1024, 0, stream>>>(Fb_a, el_a, er_a, off, deg, ssrc, partials);
    k_poolred<<<PBLK2, 128, 0, stream>>>(partials, partials2);
    k_final<<<1, 1024, 0, stream>>>(partials2, Wfc, bfc, out);
}

// Round 7
// 475.590 us; speedup vs baseline: 1.3142x; 1.0607x over previous
//
#include <hip/hip_runtime.h>

#define NN 100000   // nodes
#define NE 1600000  // edges
#define FD 128      // feature dim (4 heads x 32 ch); fp8 row = 128 B
#define NB 391      // ceil(NN/256) dst-buckets
#define CAP 4800    // padded bucket capacity (mean 4096, sigma 64 -> +11 sigma)
#define CHUNK 8192  // edges per k_bucket block -> 196 blocks
#define GB 782      // gemm tiles (128 rows each)
#define AB 25000    // agg blocks (4 nodes each, 1 node per wave)
#define PBLK2 512   // second-stage pool rows

typedef __attribute__((ext_vector_type(8))) short bf16x8;
typedef __attribute__((ext_vector_type(4))) float f32x4;

union B8 { bf16x8 v; unsigned int u[4]; };

// ---------------- helpers ----------------

__device__ __forceinline__ unsigned short f2bf(float x) {
    unsigned int u = __float_as_uint(x);
    u += 0x7fffu + ((u >> 16) & 1u);   // round-to-nearest-even
    return (unsigned short)(u >> 16);
}

__device__ __forceinline__ unsigned char f2fp8(float x) {
    // low byte of packed fp8 conversion (RNE, saturating)
    return (unsigned char)__builtin_amdgcn_cvt_pk_fp8_f32(x, 0.f, 0u, false);
}

__device__ __forceinline__ unsigned int pkhi(unsigned int ua, unsigned int ub) {
    return __builtin_amdgcn_perm(ub, ua, 0x07060302);
}

__device__ __forceinline__ void split8(const float4& x0, const float4& x1,
                                       bf16x8& hi, bf16x8& lo) {
    float f[8] = {x0.x, x0.y, x0.z, x0.w, x1.x, x1.y, x1.z, x1.w};
    B8 H, L;
#pragma unroll
    for (int i = 0; i < 4; i++) {
        unsigned int ua = __float_as_uint(f[2 * i]);
        unsigned int ub = __float_as_uint(f[2 * i + 1]);
        H.u[i] = pkhi(ua, ub);
        float ra = f[2 * i]     - __uint_as_float(ua & 0xffff0000u);
        float rb = f[2 * i + 1] - __uint_as_float(ub & 0xffff0000u);
        L.u[i] = pkhi(__float_as_uint(ra), __float_as_uint(rb));
    }
    hi = H.v; lo = L.v;
}

// ---------------- W pre-split + gcur zeroing (one dispatch) ----------------

__global__ void k_wsplit3(const float* __restrict__ W1, const float* __restrict__ W2,
                          const float* __restrict__ W3, unsigned short* __restrict__ Wth,
                          unsigned short* __restrict__ Wtl, int* __restrict__ gcur) {
    int gid = blockIdx.x * 256 + threadIdx.x;  // 0..49151
    if (gid < NB) gcur[gid] = 0;
    int w = gid >> 14;
    int tid = gid & 16383;
    const float* W = (w == 0) ? W1 : (w == 1) ? W2 : W3;
    int n = tid >> 7, k = tid & 127;
    float val = W[k * 128 + n];
    unsigned short h = f2bf(val);
    float res = val - __uint_as_float((unsigned int)h << 16);
    Wth[gid] = h;
    Wtl[gid] = f2bf(res);
}

// ---------------- bucket scatter into padded per-bucket slots ----------------
// pairs[b*CAP + slot] = src | (dst&255)<<17

__global__ __launch_bounds__(256) void k_bucket(const int* __restrict__ src,
                                                const int* __restrict__ dst,
                                                int* __restrict__ gcur,
                                                unsigned int* __restrict__ pairs) {
    __shared__ int scnt[NB];
    __shared__ int sbase[NB];
    int t = threadIdx.x;
    for (int i = t; i < NB; i += 256) scnt[i] = 0;
    __syncthreads();
    int e0 = blockIdx.x * CHUNK, e1 = min(e0 + CHUNK, NE);
    for (int i = e0 + t; i < e1; i += 256) atomicAdd(&scnt[dst[i] >> 8], 1);
    __syncthreads();
    for (int i = t; i < NB; i += 256) {
        int c = scnt[i];
        sbase[i] = (c > 0) ? (i * CAP + atomicAdd(&gcur[i], c)) : 0;
        scnt[i] = 0;  // reuse as local cursor
    }
    __syncthreads();
    for (int i = e0 + t; i < e1; i += 256) {
        int d = dst[i];
        int b = d >> 8;
        int r = atomicAdd(&scnt[b], 1);
        pairs[sbase[b] + r] = (unsigned int)src[i] | ((unsigned int)(d & 255) << 17);
    }
}

// ---------------- per-bucket counting sort body ----------------

__device__ void bsort_body(int b, const unsigned int* __restrict__ pairs,
                           const int* __restrict__ gcur, int* __restrict__ off,
                           int* __restrict__ deg, int* __restrict__ ssrc) {
    __shared__ int hcnt[256];
    __shared__ int cur[256];
    int t = threadIdx.x;
    int cnt = gcur[b];
    int estart = b * CAP;
    hcnt[t] = 0;
    __syncthreads();
    for (int i = t; i < cnt; i += 256)
        atomicAdd(&hcnt[(pairs[estart + i] >> 17) & 255], 1);
    __syncthreads();
    int v = hcnt[t];
    cur[t] = v;
    __syncthreads();
    for (int o = 1; o < 256; o <<= 1) {
        int x = (t >= o) ? cur[t - o] : 0;
        __syncthreads();
        cur[t] += x;
        __syncthreads();
    }
    int excl = cur[t] - v;
    int node = (b << 8) + t;
    if (node < NN) {
        off[node] = estart + excl;
        deg[node] = v;
    }
    __syncthreads();
    cur[t] = estart + excl;
    __syncthreads();
    for (int i = t; i < cnt; i += 256) {
        unsigned int p = pairs[estart + i];
        int pos = atomicAdd(&cur[(p >> 17) & 255], 1);
        ssrc[pos] = (int)(p & 0x1ffffu);
    }
}

// ---------------- fused GEMM epilogue (2 row-groups): fp8 features + el/er ----------------
// Features staged as fp8 bytes in wave-private LDS, then copied out as uint4
// (coalesced) — avoids 2-byte scattered global stores (partial-line RMW).

__device__ __forceinline__ void epilogue(f32x4 acc[2][8], int row0, int q, int r, int nrows,
                                         const float* __restrict__ al,
                                         const float* __restrict__ ar,
                                         unsigned char* __restrict__ FbG,
                                         float* __restrict__ el, float* __restrict__ er,
                                         unsigned char* __restrict__ sg8, int lane) {
#pragma unroll
    for (int g = 0; g < 2; g++) {
#pragma unroll
        for (int i = 0; i < 4; i++) {
            int row_l = g * 16 + q * 4 + i;
            int row = row0 + row_l;
            float elp[4], erp[4];
#pragma unroll
            for (int h = 0; h < 4; h++) { elp[h] = 0.f; erp[h] = 0.f; }
#pragma unroll
            for (int nt = 0; nt < 8; nt++) {
                int h = nt >> 1;
                int c = ((nt & 1) << 4) + r;
                float v = acc[g][nt][i];
                elp[h] = fmaf(v, al[h * 32 + c], elp[h]);
                erp[h] = fmaf(v, ar[h * 32 + c], erp[h]);
            }
#pragma unroll
            for (int o = 1; o < 16; o <<= 1) {
#pragma unroll
                for (int h = 0; h < 4; h++) {
                    elp[h] += __shfl_xor(elp[h], o);
                    erp[h] += __shfl_xor(erp[h], o);
                }
            }
#pragma unroll
            for (int nt = 0; nt < 8; nt++)
                sg8[row_l * 128 + nt * 16 + r] = f2fp8(acc[g][nt][i]);
            if (row < nrows) {
                int hh = r & 3;
                float ve = (hh & 2) ? ((hh & 1) ? elp[3] : elp[2]) : ((hh & 1) ? elp[1] : elp[0]);
                float vr = (hh & 2) ? ((hh & 1) ? erp[3] : erp[2]) : ((hh & 1) ? erp[1] : erp[0]);
                if (r < 4) el[row * 4 + hh] = ve;
                else if (r < 8) er[row * 4 + hh] = vr;
            }
        }
    }
    // copy out the wave's 32 rows (4 KB), wave-private -> no barrier needed
#pragma unroll
    for (int it = 0; it < 4; it++) {
        int off = it * 1024 + lane * 16;
        int row = row0 + (off >> 7);
        uint4 v = *(const uint4*)(sg8 + off);
        if (row < nrows) *(uint4*)(FbG + (size_t)row * FD + (off & 127)) = v;
    }
}

// ---------------- GEMM body (layer 1): A f32, hi/lo split both sides ----------------

__device__ void gemm_f32_body(int bid, const float* __restrict__ A,
                              const unsigned short* __restrict__ Wth,
                              const unsigned short* __restrict__ Wtl,
                              unsigned char* __restrict__ Fb, int nrows,
                              const float* __restrict__ al, const float* __restrict__ ar,
                              float* __restrict__ el, float* __restrict__ er) {
    __shared__ unsigned char sg8[4][4096];   // per-wave fp8 staging (32 rows x 128 B)
    int t = threadIdx.x;
    int wave = t >> 6, lane = t & 63;
    int r = lane & 15, q = lane >> 4;
    int row0 = bid * 128 + wave * 32;
    int rg0 = row0 + r, rg1 = row0 + 16 + r;

    f32x4 acc[2][8];
#pragma unroll
    for (int g = 0; g < 2; g++)
#pragma unroll
        for (int nt = 0; nt < 8; nt++) acc[g][nt] = (f32x4){0.f, 0.f, 0.f, 0.f};

#pragma unroll
    for (int ks = 0; ks < 4; ks++) {
        int k0 = ks * 32 + q * 8;
        float4 z = make_float4(0.f, 0.f, 0.f, 0.f);
        float4 a0 = z, a1 = z, b0 = z, b1 = z;
        if (rg0 < nrows) {
            const float* pa = A + (size_t)rg0 * FD + k0;
            a0 = *(const float4*)pa;
            a1 = *(const float4*)(pa + 4);
        }
        if (rg1 < nrows) {
            const float* pb = A + (size_t)rg1 * FD + k0;
            b0 = *(const float4*)pb;
            b1 = *(const float4*)(pb + 4);
        }
        bf16x8 ah0, al0, ah1, al1;
        split8(a0, a1, ah0, al0);
        split8(b0, b1, ah1, al1);
#pragma unroll
        for (int nt = 0; nt < 8; nt++) {
            int wo = ((nt * 16 + r) << 7) + k0;
            bf16x8 bh = *(const bf16x8*)(Wth + wo);
            bf16x8 bl = *(const bf16x8*)(Wtl + wo);
            acc[0][nt] = __builtin_amdgcn_mfma_f32_16x16x32_bf16(ah0, bh, acc[0][nt], 0, 0, 0);
            acc[0][nt] = __builtin_amdgcn_mfma_f32_16x16x32_bf16(al0, bh, acc[0][nt], 0, 0, 0);
            acc[0][nt] = __builtin_amdgcn_mfma_f32_16x16x32_bf16(ah0, bl, acc[0][nt], 0, 0, 0);
            acc[1][nt] = __builtin_amdgcn_mfma_f32_16x16x32_bf16(ah1, bh, acc[1][nt], 0, 0, 0);
            acc[1][nt] = __builtin_amdgcn_mfma_f32_16x16x32_bf16(al1, bh, acc[1][nt], 0, 0, 0);
            acc[1][nt] = __builtin_amdgcn_mfma_f32_16x16x32_bf16(ah1, bl, acc[1][nt], 0, 0, 0);
        }
    }
    epilogue(acc, row0, q, r, nrows, al, ar, Fb, el, er, sg8[wave], lane);
}

// ---------------- fused dispatch: bsort (blocks 0..NB-1) + layer-1 GEMM (rest) ----------------

__global__ __launch_bounds__(256) void k_sortgemm1(const unsigned int* __restrict__ pairs,
                                                   const int* __restrict__ gcur,
                                                   int* __restrict__ off, int* __restrict__ deg,
                                                   int* __restrict__ ssrc,
                                                   const float* __restrict__ A,
                                                   const unsigned short* __restrict__ Wth,
                                                   const unsigned short* __restrict__ Wtl,
                                                   unsigned char* __restrict__ Fb,
                                                   const float* __restrict__ al,
                                                   const float* __restrict__ ar,
                                                   float* __restrict__ el,
                                                   float* __restrict__ er) {
    int b = blockIdx.x;
    if (b < NB) bsort_body(b, pairs, gcur, off, deg, ssrc);
    else gemm_f32_body(b - NB, A, Wth, Wtl, Fb, NN, al, ar, el, er);
}

// ---------------- wave-wide aggregation of one dst node (relu'd output) ----------------
// Features gathered as fp8 (8 B/lane), dequant via v_cvt_pk_f32_fp8.
// Result: acc8[z] = relu(H[d][8*(lane&15)+z]), replicated across 4 lane-groups.

__device__ __forceinline__ void agg_node(int d,
        const unsigned char* __restrict__ Fb,
        const float* __restrict__ el, const float* __restrict__ er,
        const int* __restrict__ off, const int* __restrict__ deg_,
        const int* __restrict__ ssrc, int lane, float acc8[8]) {
#pragma unroll
    for (int z = 0; z < 8; z++) acc8[z] = 0.f;
    int start = off[d];
    int dg = deg_[d];
    if (dg > 0) {
        int h = lane & 3;
        int eloc = lane >> 2;
        int g = lane >> 4;
        int c16 = lane & 15;
        int hsel2 = c16 >> 2;
        float er_h = er[d * 4 + h];
        float s = 0.f;
        for (int base = 0; base < dg; base += 16) {
            int i = base + eloc;
            float a = 0.f;
            int sid = 0;  // invalid lanes -> row 0 with weight 0 (L1-hot, harmless)
            if (i < dg) {
                sid = ssrc[start + i];
                float v = el[sid * 4 + h] + er_h;
                float e = v > 0.f ? v : 0.2f * v;
                a = __expf(e);
            }
            s += a;
#pragma unroll
            for (int k = 0; k < 4; k++) {
                int sl = 16 * k + 4 * g;               // lane holding sid of row 4k+g
                int sid_v = __shfl(sid, sl, 64);
                float av = __shfl(a, sl + hsel2, 64);  // alpha for my head
                uint2 u = *(const uint2*)(Fb + (size_t)sid_v * FD + c16 * 8);
                {
                    auto p = __builtin_amdgcn_cvt_pk_f32_fp8(u.x, false);
                    acc8[0] = fmaf(av, p[0], acc8[0]);
                    acc8[1] = fmaf(av, p[1], acc8[1]);
                }
                {
                    auto p = __builtin_amdgcn_cvt_pk_f32_fp8(u.x, true);
                    acc8[2] = fmaf(av, p[0], acc8[2]);
                    acc8[3] = fmaf(av, p[1], acc8[3]);
                }
                {
                    auto p = __builtin_amdgcn_cvt_pk_f32_fp8(u.y, false);
                    acc8[4] = fmaf(av, p[0], acc8[4]);
                    acc8[5] = fmaf(av, p[1], acc8[5]);
                }
                {
                    auto p = __builtin_amdgcn_cvt_pk_f32_fp8(u.y, true);
                    acc8[6] = fmaf(av, p[0], acc8[6]);
                    acc8[7] = fmaf(av, p[1], acc8[7]);
                }
            }
        }
        // merge the 4 row-groups (results become replicated wave-wide)
#pragma unroll
        for (int z = 0; z < 8; z++) {
            acc8[z] += __shfl_xor(acc8[z], 16, 64);
            acc8[z] += __shfl_xor(acc8[z], 32, 64);
        }
        for (int o = 4; o < 64; o <<= 1) s += __shfl_xor(s, o, 64);
        float inv = 1.f / __shfl(s, hsel2, 64);
#pragma unroll
        for (int z = 0; z < 8; z++) acc8[z] *= inv;
    }
#pragma unroll
    for (int z = 0; z < 8; z++) acc8[z] = fmaxf(acc8[z], 0.f);   // relu (all 3 layers)
}

// ---------------- standalone agg: 4 waves/block, 1 node/wave, bf16 Hb out ----------------
// 25K blocks -> fine-grained load balancing (no 16-wave barrier tail, no idle
// GEMM phase). Coalesced 256 B uint4 row writes by 16 lanes of group 0.

__global__ __launch_bounds__(256) void k_agg8(
        const unsigned char* __restrict__ Fb,
        const float* __restrict__ el, const float* __restrict__ er,
        const int* __restrict__ off, const int* __restrict__ deg_,
        const int* __restrict__ ssrc,
        unsigned int* __restrict__ Hb) {
    int wave = threadIdx.x >> 6, lane = threadIdx.x & 63;
    int d = blockIdx.x * 4 + wave;
    if (d >= NN) return;
    float acc8[8];
    agg_node(d, Fb, el, er, off, deg_, ssrc, lane, acc8);
    int c16 = lane & 15, g = lane >> 4;
    if (g == 0) {   // 16 lanes write the packed bf16 row (256 B contiguous)
        uint4 pk;
        pk.x = ((unsigned int)f2bf(acc8[1]) << 16) | f2bf(acc8[0]);
        pk.y = ((unsigned int)f2bf(acc8[3]) << 16) | f2bf(acc8[2]);
        pk.z = ((unsigned int)f2bf(acc8[5]) << 16) | f2bf(acc8[4]);
        pk.w = ((unsigned int)f2bf(acc8[7]) << 16) | f2bf(acc8[6]);
        *(uint4*)(Hb + (size_t)d * 64 + c16 * 4) = pk;
    }
}

// ---------------- GEMM (layers 2,3): A bf16 (Hb), fp8 out via LDS staging ----------------

__global__ __launch_bounds__(256) void k_gemm8(const unsigned short* __restrict__ A,
                                               const unsigned short* __restrict__ Wth,
                                               const unsigned short* __restrict__ Wtl,
                                               unsigned char* __restrict__ Fb,
                                               const float* __restrict__ al,
                                               const float* __restrict__ ar,
                                               float* __restrict__ el,
                                               float* __restrict__ er) {
    __shared__ unsigned char sg8[4][4096];   // per-wave fp8 staging (32 rows x 128 B)
    int t = threadIdx.x;
    int wave = t >> 6, lane = t & 63;
    int r = lane & 15, q = lane >> 4;
    int row0 = blockIdx.x * 128 + wave * 32;
    int rg0 = row0 + r, rg1 = row0 + 16 + r;

    f32x4 acc[2][8];
#pragma unroll
    for (int g = 0; g < 2; g++)
#pragma unroll
        for (int nt = 0; nt < 8; nt++) acc[g][nt] = (f32x4){0.f, 0.f, 0.f, 0.f};

#pragma unroll
    for (int ks = 0; ks < 4; ks++) {
        int k0 = ks * 32 + q * 8;
        bf16x8 a0 = {0, 0, 0, 0, 0, 0, 0, 0};
        bf16x8 a1 = {0, 0, 0, 0, 0, 0, 0, 0};
        if (rg0 < NN) a0 = *(const bf16x8*)(A + (size_t)rg0 * FD + k0);
        if (rg1 < NN) a1 = *(const bf16x8*)(A + (size_t)rg1 * FD + k0);
#pragma unroll
        for (int nt = 0; nt < 8; nt++) {
            int wo = ((nt * 16 + r) << 7) + k0;
            bf16x8 bh = *(const bf16x8*)(Wth + wo);
            bf16x8 bl = *(const bf16x8*)(Wtl + wo);
            acc[0][nt] = __builtin_amdgcn_mfma_f32_16x16x32_bf16(a0, bh, acc[0][nt], 0, 0, 0);
            acc[0][nt] = __builtin_amdgcn_mfma_f32_16x16x32_bf16(a0, bl, acc[0][nt], 0, 0, 0);
            acc[1][nt] = __builtin_amdgcn_mfma_f32_16x16x32_bf16(a1, bh, acc[1][nt], 0, 0, 0);
            acc[1][nt] = __builtin_amdgcn_mfma_f32_16x16x32_bf16(a1, bl, acc[1][nt], 0, 0, 0);
        }
    }
    epilogue(acc, row0, q, r, NN, al, ar, Fb, el, er, sg8[wave], lane);
}

// ---------------- fused agg (layer 3) + block-local max pool (4-wave barrier) ----------------

__global__ __launch_bounds__(256) void k_aggpool8(
        const unsigned char* __restrict__ Fb,
        const float* __restrict__ el, const float* __restrict__ er,
        const int* __restrict__ off, const int* __restrict__ deg_,
        const int* __restrict__ ssrc,
        float* __restrict__ partials) {
    __shared__ float wmax[4][128];
    int t = threadIdx.x;
    int wave = t >> 6, lane = t & 63;
    int c16 = lane & 15, g = lane >> 4;
    int d = blockIdx.x * 4 + wave;
    float acc8[8];
    if (d < NN) {
        agg_node(d, Fb, el, er, off, deg_, ssrc, lane, acc8);
    } else {
#pragma unroll
        for (int z = 0; z < 8; z++) acc8[z] = 0.f;
    }
    if (g == 0) {
#pragma unroll
        for (int z = 0; z < 8; z++) wmax[wave][c16 * 8 + z] = acc8[z];
    }
    __syncthreads();
    if (t < 128) {
        float m = fmaxf(fmaxf(wmax[0][t], wmax[1][t]), fmaxf(wmax[2][t], wmax[3][t]));
        partials[(size_t)blockIdx.x * 128 + t] = m;
    }
}

// ---------------- pool reduce: AB partial rows -> PBLK2 rows (contiguous chunks) ----------------

__global__ __launch_bounds__(128) void k_poolred(const float* __restrict__ partials,
                                                 float* __restrict__ partials2) {
    int c = threadIdx.x;         // channel 0..127
    int b = blockIdx.x;          // 0..PBLK2-1
    const int R = (AB + PBLK2 - 1) / PBLK2;   // 49
    int r0 = b * R, r1 = min(AB, r0 + R);
    float m = 0.f;
    for (int r = r0; r < r1; ++r)
        m = fmaxf(m, partials[(size_t)r * 128 + c]);
    partials2[(size_t)b * 128 + c] = m;
}

// ---------------- final: reduce partials2 + bf16-round + FC + softmax (1 block) ----------------

__global__ __launch_bounds__(1024) void k_final(const float* __restrict__ partials2,
                                                const float* __restrict__ Wfc,
                                                const float* __restrict__ bfc,
                                                float* __restrict__ outp) {
    __shared__ float red[1024];
    int t = threadIdx.x;
    int c = t & 127;             // channel
    int slice = t >> 7;          // 8 row-slices of 64 rows each
    float m = 0.f;
    int i0 = slice * (PBLK2 / 8);
#pragma unroll
    for (int k = 0; k < PBLK2 / 8; ++k)
        m = fmaxf(m, partials2[(size_t)(i0 + k) * 128 + c]);
    red[t] = m;
    __syncthreads();
    if (t < 128) {
        float v = red[t];
#pragma unroll
        for (int s = 1; s < 8; ++s) v = fmaxf(v, red[s * 128 + t]);
        // bf16-round the pooled value (matches the prior pipeline numerics)
        red[t] = __uint_as_float((unsigned int)f2bf(v) << 16);
    }
    __syncthreads();
    if (t < 64) {
        int j = t & 7;
        int kk = t >> 3;
        float partial = 0.f;
        for (int k = kk * 16; k < kk * 16 + 16; ++k) partial += red[k] * Wfc[k * 8 + j];
        for (int o = 8; o < 64; o <<= 1) partial += __shfl_xor(partial, o);
        float logit = partial + bfc[j];
        float mxl = logit;
        for (int o = 1; o < 8; o <<= 1) mxl = fmaxf(mxl, __shfl_xor(mxl, o));
        float ex = __expf(logit - mxl);
        float sm = ex;
        for (int o = 1; o < 8; o <<= 1) sm += __shfl_xor(sm, o);
        if (t < 8) outp[t] = ex / sm;
    }
}

// ---------------- launch ----------------

extern "C" void kernel_launch(void* const* d_in, const int* in_sizes, int n_in,
                              void* d_out, int out_size, void* d_ws, size_t ws_size,
                              hipStream_t stream) {
    const float* x   = (const float*)d_in[0];
    const int*   src = (const int*)d_in[1];
    const int*   dst = (const int*)d_in[2];
    const float* W1  = (const float*)d_in[3];
    const float* al1 = (const float*)d_in[4];
    const float* ar1 = (const float*)d_in[5];
    const float* W2  = (const float*)d_in[6];
    const float* al2 = (const float*)d_in[7];
    const float* ar2 = (const float*)d_in[8];
    const float* W3  = (const float*)d_in[9];
    const float* al3 = (const float*)d_in[10];
    const float* ar3 = (const float*)d_in[11];
    const float* Wfc = (const float*)d_in[12];
    const float* bfc = (const float*)d_in[13];
    float* out = (float*)d_out;

    char* p = (char*)d_ws;
    auto alloc = [&](size_t bytes) {
        char* r = p;
        p += (bytes + 255) & ~(size_t)255;
        return r;
    };
    unsigned char* Fb_a = (unsigned char*)alloc((size_t)NN * FD);   // fp8 features
    unsigned char* Fb_b = (unsigned char*)alloc((size_t)NN * FD);
    unsigned int*  Hb   = (unsigned int*)alloc((size_t)NN * 64 * 4); // bf16x2-packed H
    float* el_a   = (float*)alloc((size_t)NN * 4 * 4);
    float* er_a   = (float*)alloc((size_t)NN * 4 * 4);
    int*   off    = (int*)alloc((size_t)NN * 4);
    int*   deg    = (int*)alloc((size_t)NN * 4);
    int*   ssrc   = (int*)alloc((size_t)NB * CAP * 4);
    unsigned int* pairs = (unsigned int*)alloc((size_t)NB * CAP * 4);
    int*   gcur   = (int*)alloc((size_t)NB * 4);
    float* partials  = (float*)alloc((size_t)AB * 128 * 4);     // 12.8 MB
    float* partials2 = (float*)alloc((size_t)PBLK2 * 128 * 4);  // 256 KB
    unsigned short* Wth = (unsigned short*)alloc(3 * 16384 * 2);
    unsigned short* Wtl = (unsigned short*)alloc(3 * 16384 * 2);
    // pairs (7.5 MB) is dead after k_sortgemm1's bsort -> overlay layer-B el/er (3.2 MB)
    float* el_b = (float*)pairs;
    float* er_b = (float*)pairs + (size_t)NN * 4;

    const int BB = (NE + CHUNK - 1) / CHUNK;  // 196

    k_wsplit3<<<192, 256, 0, stream>>>(W1, W2, W3, Wth, Wtl, gcur);
    k_bucket<<<BB, 256, 0, stream>>>(src, dst, gcur, pairs);

    // bsort + layer-1 GEMM fused (independent work) -> Fb_a (fp8), el_a, er_a
    k_sortgemm1<<<NB + GB, 256, 0, stream>>>(pairs, gcur, off, deg, ssrc,
                                             x, Wth, Wtl, Fb_a, al1, ar1, el_a, er_a);
    // layer-1 agg -> Hb (bf16)
    k_agg8<<<AB, 256, 0, stream>>>(Fb_a, el_a, er_a, off, deg, ssrc, Hb);
    // layer-2 GEMM: Hb -> Fb_b (fp8), el_b, er_b
    k_gemm8<<<GB, 256, 0, stream>>>((const unsigned short*)Hb, Wth + 16384, Wtl + 16384,
                                    Fb_b, al2, ar2, el_b, er_b);
    // layer-2 agg -> Hb
    k_agg8<<<AB, 256, 0, stream>>>(Fb_b, el_b, er_b, off, deg, ssrc, Hb);
    // layer-3 GEMM: Hb -> Fb_a (fp8), el_a, er_a
    k_gemm8<<<GB, 256, 0, stream>>>((const unsigned short*)Hb, Wth + 32768, Wtl + 32768,
                                    Fb_a, al3, ar3, el_a, er_a);
    // layer-3 agg + block-local max pool
    k_aggpool8<<<AB, 256, 0, stream>>>(Fb_a, el_a, er_a, off, deg, ssrc, partials);
    k_poolred<<<PBLK2, 128, 0, stream>>>(partials, partials2);
    k_final<<<1, 1024, 0, stream>>>(partials2, Wfc, bfc, out);
}

// Round 8
// 428.223 us; speedup vs baseline: 1.4595x; 1.1106x over previous
//
#include <hip/hip_runtime.h>

#define NN 100000   // nodes
#define NE 1600000  // edges
#define FD 128      // feature dim (4 heads x 32 ch); fp8 row = 128 B
#define NB 391      // ceil(NN/256) dst-buckets
#define CAP 4800    // padded bucket capacity (mean 4096, sigma 64 -> +11 sigma)
#define CHUNK 8192  // edges per k_bucket block -> 196 blocks
#define GB 782      // gemm tiles (128 rows each)
#define AB 25000    // agg blocks (4 nodes each, 1 node per wave)
#define PBLK2 512   // second-stage pool rows

typedef __attribute__((ext_vector_type(8))) short bf16x8;
typedef __attribute__((ext_vector_type(4))) float f32x4;

union B8 { bf16x8 v; unsigned int u[4]; };

// ---------------- helpers ----------------

__device__ __forceinline__ unsigned short f2bf(float x) {
    unsigned int u = __float_as_uint(x);
    u += 0x7fffu + ((u >> 16) & 1u);   // round-to-nearest-even
    return (unsigned short)(u >> 16);
}

__device__ __forceinline__ unsigned char f2fp8(float x) {
    // low byte of packed fp8 conversion (RNE, saturating)
    return (unsigned char)__builtin_amdgcn_cvt_pk_fp8_f32(x, 0.f, 0u, false);
}

__device__ __forceinline__ unsigned int pkhi(unsigned int ua, unsigned int ub) {
    return __builtin_amdgcn_perm(ub, ua, 0x07060302);
}

// pack 8 f32 -> 8 bf16 (truncate-to-hi path is replaced by RNE via pkhi on raw bits;
// here we keep the original hi-split semantics: hi = top 16 bits (truncation)).
// NOTE: truncation (not RNE) matches the previous hi/lo split's hi part, keeping
// layer-1 feature values on the same quantization grid as all passing rounds.
__device__ __forceinline__ bf16x8 pack8hi(const float4& x0, const float4& x1) {
    float f[8] = {x0.x, x0.y, x0.z, x0.w, x1.x, x1.y, x1.z, x1.w};
    B8 H;
#pragma unroll
    for (int i = 0; i < 4; i++) {
        unsigned int ua = __float_as_uint(f[2 * i]);
        unsigned int ub = __float_as_uint(f[2 * i + 1]);
        H.u[i] = pkhi(ua, ub);
    }
    return H.v;
}

// ---------------- W -> bf16 + gcur zeroing (one dispatch) ----------------

__global__ void k_wsplit(const float* __restrict__ W1, const float* __restrict__ W2,
                         const float* __restrict__ W3, unsigned short* __restrict__ Wth,
                         int* __restrict__ gcur) {
    int gid = blockIdx.x * 256 + threadIdx.x;  // 0..49151
    if (gid < NB) gcur[gid] = 0;
    int w = gid >> 14;
    int tid = gid & 16383;
    const float* W = (w == 0) ? W1 : (w == 1) ? W2 : W3;
    int n = tid >> 7, k = tid & 127;
    Wth[gid] = f2bf(W[k * 128 + n]);   // RNE bf16 weights
}

// ---------------- bucket scatter into padded per-bucket slots ----------------
// pairs[b*CAP + slot] = src | (dst&255)<<17

__global__ __launch_bounds__(256) void k_bucket(const int* __restrict__ src,
                                                const int* __restrict__ dst,
                                                int* __restrict__ gcur,
                                                unsigned int* __restrict__ pairs) {
    __shared__ int scnt[NB];
    __shared__ int sbase[NB];
    int t = threadIdx.x;
    for (int i = t; i < NB; i += 256) scnt[i] = 0;
    __syncthreads();
    int e0 = blockIdx.x * CHUNK, e1 = min(e0 + CHUNK, NE);
    for (int i = e0 + t; i < e1; i += 256) atomicAdd(&scnt[dst[i] >> 8], 1);
    __syncthreads();
    for (int i = t; i < NB; i += 256) {
        int c = scnt[i];
        sbase[i] = (c > 0) ? (i * CAP + atomicAdd(&gcur[i], c)) : 0;
        scnt[i] = 0;  // reuse as local cursor
    }
    __syncthreads();
    for (int i = e0 + t; i < e1; i += 256) {
        int d = dst[i];
        int b = d >> 8;
        int r = atomicAdd(&scnt[b], 1);
        pairs[sbase[b] + r] = (unsigned int)src[i] | ((unsigned int)(d & 255) << 17);
    }
}

// ---------------- per-bucket counting sort body ----------------

__device__ void bsort_body(int b, const unsigned int* __restrict__ pairs,
                           const int* __restrict__ gcur, int* __restrict__ off,
                           int* __restrict__ deg, int* __restrict__ ssrc) {
    __shared__ int hcnt[256];
    __shared__ int cur[256];
    int t = threadIdx.x;
    int cnt = gcur[b];
    int estart = b * CAP;
    hcnt[t] = 0;
    __syncthreads();
    for (int i = t; i < cnt; i += 256)
        atomicAdd(&hcnt[(pairs[estart + i] >> 17) & 255], 1);
    __syncthreads();
    int v = hcnt[t];
    cur[t] = v;
    __syncthreads();
    for (int o = 1; o < 256; o <<= 1) {
        int x = (t >= o) ? cur[t - o] : 0;
        __syncthreads();
        cur[t] += x;
        __syncthreads();
    }
    int excl = cur[t] - v;
    int node = (b << 8) + t;
    if (node < NN) {
        off[node] = estart + excl;
        deg[node] = v;
    }
    __syncthreads();
    cur[t] = estart + excl;
    __syncthreads();
    for (int i = t; i < cnt; i += 256) {
        unsigned int p = pairs[estart + i];
        int pos = atomicAdd(&cur[(p >> 17) & 255], 1);
        ssrc[pos] = (int)(p & 0x1ffffu);
    }
}

// ---------------- fused GEMM epilogue (2 row-groups): fp8 features + el/er ----------------
// Features staged as fp8 bytes in wave-private LDS, then copied out as uint4
// (coalesced) — avoids 1-byte scattered global stores (partial-line RMW).

__device__ __forceinline__ void epilogue(f32x4 acc[2][8], int row0, int q, int r, int nrows,
                                         const float* __restrict__ al,
                                         const float* __restrict__ ar,
                                         unsigned char* __restrict__ FbG,
                                         float* __restrict__ el, float* __restrict__ er,
                                         unsigned char* __restrict__ sg8, int lane) {
#pragma unroll
    for (int g = 0; g < 2; g++) {
#pragma unroll
        for (int i = 0; i < 4; i++) {
            int row_l = g * 16 + q * 4 + i;
            int row = row0 + row_l;
            float elp[4], erp[4];
#pragma unroll
            for (int h = 0; h < 4; h++) { elp[h] = 0.f; erp[h] = 0.f; }
#pragma unroll
            for (int nt = 0; nt < 8; nt++) {
                int h = nt >> 1;
                int c = ((nt & 1) << 4) + r;
                float v = acc[g][nt][i];
                elp[h] = fmaf(v, al[h * 32 + c], elp[h]);
                erp[h] = fmaf(v, ar[h * 32 + c], erp[h]);
            }
#pragma unroll
            for (int o = 1; o < 16; o <<= 1) {
#pragma unroll
                for (int h = 0; h < 4; h++) {
                    elp[h] += __shfl_xor(elp[h], o);
                    erp[h] += __shfl_xor(erp[h], o);
                }
            }
#pragma unroll
            for (int nt = 0; nt < 8; nt++)
                sg8[row_l * 128 + nt * 16 + r] = f2fp8(acc[g][nt][i]);
            if (row < nrows) {
                int hh = r & 3;
                float ve = (hh & 2) ? ((hh & 1) ? elp[3] : elp[2]) : ((hh & 1) ? elp[1] : elp[0]);
                float vr = (hh & 2) ? ((hh & 1) ? erp[3] : erp[2]) : ((hh & 1) ? erp[1] : erp[0]);
                if (r < 4) el[row * 4 + hh] = ve;
                else if (r < 8) er[row * 4 + hh] = vr;
            }
        }
    }
    // copy out the wave's 32 rows (4 KB), wave-private -> no barrier needed
#pragma unroll
    for (int it = 0; it < 4; it++) {
        int off = it * 1024 + lane * 16;
        int row = row0 + (off >> 7);
        uint4 v = *(const uint4*)(sg8 + off);
        if (row < nrows) *(uint4*)(FbG + (size_t)row * FD + (off & 127)) = v;
    }
}

// ---------------- GEMM body (layer 1): A f32 -> bf16, single MFMA per tile ----------------

__device__ void gemm_f32_body(int bid, const float* __restrict__ A,
                              const unsigned short* __restrict__ Wth,
                              unsigned char* __restrict__ Fb, int nrows,
                              const float* __restrict__ al, const float* __restrict__ ar,
                              float* __restrict__ el, float* __restrict__ er) {
    __shared__ unsigned char sg8[4][4096];   // per-wave fp8 staging (32 rows x 128 B)
    int t = threadIdx.x;
    int wave = t >> 6, lane = t & 63;
    int r = lane & 15, q = lane >> 4;
    int row0 = bid * 128 + wave * 32;
    int rg0 = row0 + r, rg1 = row0 + 16 + r;

    f32x4 acc[2][8];
#pragma unroll
    for (int g = 0; g < 2; g++)
#pragma unroll
        for (int nt = 0; nt < 8; nt++) acc[g][nt] = (f32x4){0.f, 0.f, 0.f, 0.f};

#pragma unroll
    for (int ks = 0; ks < 4; ks++) {
        int k0 = ks * 32 + q * 8;
        float4 z = make_float4(0.f, 0.f, 0.f, 0.f);
        float4 a0 = z, a1 = z, b0 = z, b1 = z;
        if (rg0 < nrows) {
            const float* pa = A + (size_t)rg0 * FD + k0;
            a0 = *(const float4*)pa;
            a1 = *(const float4*)(pa + 4);
        }
        if (rg1 < nrows) {
            const float* pb = A + (size_t)rg1 * FD + k0;
            b0 = *(const float4*)pb;
            b1 = *(const float4*)(pb + 4);
        }
        bf16x8 ah0 = pack8hi(a0, a1);
        bf16x8 ah1 = pack8hi(b0, b1);
#pragma unroll
        for (int nt = 0; nt < 8; nt++) {
            int wo = ((nt * 16 + r) << 7) + k0;
            bf16x8 bh = *(const bf16x8*)(Wth + wo);
            acc[0][nt] = __builtin_amdgcn_mfma_f32_16x16x32_bf16(ah0, bh, acc[0][nt], 0, 0, 0);
            acc[1][nt] = __builtin_amdgcn_mfma_f32_16x16x32_bf16(ah1, bh, acc[1][nt], 0, 0, 0);
        }
    }
    epilogue(acc, row0, q, r, nrows, al, ar, Fb, el, er, sg8[wave], lane);
}

// ---------------- fused dispatch: bsort (blocks 0..NB-1) + layer-1 GEMM (rest) ----------------

__global__ __launch_bounds__(256) void k_sortgemm1(const unsigned int* __restrict__ pairs,
                                                   const int* __restrict__ gcur,
                                                   int* __restrict__ off, int* __restrict__ deg,
                                                   int* __restrict__ ssrc,
                                                   const float* __restrict__ A,
                                                   const unsigned short* __restrict__ Wth,
                                                   unsigned char* __restrict__ Fb,
                                                   const float* __restrict__ al,
                                                   const float* __restrict__ ar,
                                                   float* __restrict__ el,
                                                   float* __restrict__ er) {
    int b = blockIdx.x;
    if (b < NB) bsort_body(b, pairs, gcur, off, deg, ssrc);
    else gemm_f32_body(b - NB, A, Wth, Fb, NN, al, ar, el, er);
}

// ---------------- wave-wide aggregation of one dst node (relu'd output) ----------------
// Features gathered as fp8 (8 B/lane), dequant via v_cvt_pk_f32_fp8.
// Result: acc8[z] = relu(H[d][8*(lane&15)+z]), replicated across 4 lane-groups.

__device__ __forceinline__ void agg_node(int d,
        const unsigned char* __restrict__ Fb,
        const float* __restrict__ el, const float* __restrict__ er,
        const int* __restrict__ off, const int* __restrict__ deg_,
        const int* __restrict__ ssrc, int lane, float acc8[8]) {
#pragma unroll
    for (int z = 0; z < 8; z++) acc8[z] = 0.f;
    int start = off[d];
    int dg = deg_[d];
    if (dg > 0) {
        int h = lane & 3;
        int eloc = lane >> 2;
        int g = lane >> 4;
        int c16 = lane & 15;
        int hsel2 = c16 >> 2;
        float er_h = er[d * 4 + h];
        float s = 0.f;
        for (int base = 0; base < dg; base += 16) {
            int i = base + eloc;
            float a = 0.f;
            int sid = 0;  // invalid lanes -> row 0 with weight 0 (L1-hot, harmless)
            if (i < dg) {
                sid = ssrc[start + i];
                float v = el[sid * 4 + h] + er_h;
                float e = v > 0.f ? v : 0.2f * v;
                a = __expf(e);
            }
            s += a;
#pragma unroll
            for (int k = 0; k < 4; k++) {
                int sl = 16 * k + 4 * g;               // lane holding sid of row 4k+g
                int sid_v = __shfl(sid, sl, 64);
                float av = __shfl(a, sl + hsel2, 64);  // alpha for my head
                uint2 u = *(const uint2*)(Fb + (size_t)sid_v * FD + c16 * 8);
                {
                    auto p = __builtin_amdgcn_cvt_pk_f32_fp8(u.x, false);
                    acc8[0] = fmaf(av, p[0], acc8[0]);
                    acc8[1] = fmaf(av, p[1], acc8[1]);
                }
                {
                    auto p = __builtin_amdgcn_cvt_pk_f32_fp8(u.x, true);
                    acc8[2] = fmaf(av, p[0], acc8[2]);
                    acc8[3] = fmaf(av, p[1], acc8[3]);
                }
                {
                    auto p = __builtin_amdgcn_cvt_pk_f32_fp8(u.y, false);
                    acc8[4] = fmaf(av, p[0], acc8[4]);
                    acc8[5] = fmaf(av, p[1], acc8[5]);
                }
                {
                    auto p = __builtin_amdgcn_cvt_pk_f32_fp8(u.y, true);
                    acc8[6] = fmaf(av, p[0], acc8[6]);
                    acc8[7] = fmaf(av, p[1], acc8[7]);
                }
            }
        }
        // merge the 4 row-groups (results become replicated wave-wide)
#pragma unroll
        for (int z = 0; z < 8; z++) {
            acc8[z] += __shfl_xor(acc8[z], 16, 64);
            acc8[z] += __shfl_xor(acc8[z], 32, 64);
        }
        for (int o = 4; o < 64; o <<= 1) s += __shfl_xor(s, o, 64);
        float inv = 1.f / __shfl(s, hsel2, 64);
#pragma unroll
        for (int z = 0; z < 8; z++) acc8[z] *= inv;
    }
#pragma unroll
    for (int z = 0; z < 8; z++) acc8[z] = fmaxf(acc8[z], 0.f);   // relu (all 3 layers)
}

// ---------------- standalone agg: 4 waves/block, 1 node/wave, bf16 Hb out ----------------

__global__ __launch_bounds__(256) void k_agg8(
        const unsigned char* __restrict__ Fb,
        const float* __restrict__ el, const float* __restrict__ er,
        const int* __restrict__ off, const int* __restrict__ deg_,
        const int* __restrict__ ssrc,
        unsigned int* __restrict__ Hb) {
    int wave = threadIdx.x >> 6, lane = threadIdx.x & 63;
    int d = blockIdx.x * 4 + wave;
    if (d >= NN) return;
    float acc8[8];
    agg_node(d, Fb, el, er, off, deg_, ssrc, lane, acc8);
    int c16 = lane & 15, g = lane >> 4;
    if (g == 0) {   // 16 lanes write the packed bf16 row (256 B contiguous)
        uint4 pk;
        pk.x = ((unsigned int)f2bf(acc8[1]) << 16) | f2bf(acc8[0]);
        pk.y = ((unsigned int)f2bf(acc8[3]) << 16) | f2bf(acc8[2]);
        pk.z = ((unsigned int)f2bf(acc8[5]) << 16) | f2bf(acc8[4]);
        pk.w = ((unsigned int)f2bf(acc8[7]) << 16) | f2bf(acc8[6]);
        *(uint4*)(Hb + (size_t)d * 64 + c16 * 4) = pk;
    }
}

// ---------------- GEMM (layers 2,3): A bf16 (Hb), single MFMA, fp8 out ----------------

__global__ __launch_bounds__(256) void k_gemm8(const unsigned short* __restrict__ A,
                                               const unsigned short* __restrict__ Wth,
                                               unsigned char* __restrict__ Fb,
                                               const float* __restrict__ al,
                                               const float* __restrict__ ar,
                                               float* __restrict__ el,
                                               float* __restrict__ er) {
    __shared__ unsigned char sg8[4][4096];   // per-wave fp8 staging (32 rows x 128 B)
    int t = threadIdx.x;
    int wave = t >> 6, lane = t & 63;
    int r = lane & 15, q = lane >> 4;
    int row0 = blockIdx.x * 128 + wave * 32;
    int rg0 = row0 + r, rg1 = row0 + 16 + r;

    f32x4 acc[2][8];
#pragma unroll
    for (int g = 0; g < 2; g++)
#pragma unroll
        for (int nt = 0; nt < 8; nt++) acc[g][nt] = (f32x4){0.f, 0.f, 0.f, 0.f};

#pragma unroll
    for (int ks = 0; ks < 4; ks++) {
        int k0 = ks * 32 + q * 8;
        bf16x8 a0 = {0, 0, 0, 0, 0, 0, 0, 0};
        bf16x8 a1 = {0, 0, 0, 0, 0, 0, 0, 0};
        if (rg0 < NN) a0 = *(const bf16x8*)(A + (size_t)rg0 * FD + k0);
        if (rg1 < NN) a1 = *(const bf16x8*)(A + (size_t)rg1 * FD + k0);
#pragma unroll
        for (int nt = 0; nt < 8; nt++) {
            int wo = ((nt * 16 + r) << 7) + k0;
            bf16x8 bh = *(const bf16x8*)(Wth + wo);
            acc[0][nt] = __builtin_amdgcn_mfma_f32_16x16x32_bf16(a0, bh, acc[0][nt], 0, 0, 0);
            acc[1][nt] = __builtin_amdgcn_mfma_f32_16x16x32_bf16(a1, bh, acc[1][nt], 0, 0, 0);
        }
    }
    epilogue(acc, row0, q, r, NN, al, ar, Fb, el, er, sg8[wave], lane);
}

// ---------------- fused agg (layer 3) + block-local max pool (4-wave barrier) ----------------

__global__ __launch_bounds__(256) void k_aggpool8(
        const unsigned char* __restrict__ Fb,
        const float* __restrict__ el, const float* __restrict__ er,
        const int* __restrict__ off, const int* __restrict__ deg_,
        const int* __restrict__ ssrc,
        float* __restrict__ partials) {
    __shared__ float wmax[4][128];
    int t = threadIdx.x;
    int wave = t >> 6, lane = t & 63;
    int c16 = lane & 15, g = lane >> 4;
    int d = blockIdx.x * 4 + wave;
    float acc8[8];
    if (d < NN) {
        agg_node(d, Fb, el, er, off, deg_, ssrc, lane, acc8);
    } else {
#pragma unroll
        for (int z = 0; z < 8; z++) acc8[z] = 0.f;
    }
    if (g == 0) {
#pragma unroll
        for (int z = 0; z < 8; z++) wmax[wave][c16 * 8 + z] = acc8[z];
    }
    __syncthreads();
    if (t < 128) {
        float m = fmaxf(fmaxf(wmax[0][t], wmax[1][t]), fmaxf(wmax[2][t], wmax[3][t]));
        partials[(size_t)blockIdx.x * 128 + t] = m;
    }
}

// ---------------- pool reduce: AB partial rows -> PBLK2 rows (contiguous chunks) ----------------

__global__ __launch_bounds__(128) void k_poolred(const float* __restrict__ partials,
                                                 float* __restrict__ partials2) {
    int c = threadIdx.x;         // channel 0..127
    int b = blockIdx.x;          // 0..PBLK2-1
    const int R = (AB + PBLK2 - 1) / PBLK2;   // 49
    int r0 = b * R, r1 = min(AB, r0 + R);
    float m = 0.f;
    for (int r = r0; r < r1; ++r)
        m = fmaxf(m, partials[(size_t)r * 128 + c]);
    partials2[(size_t)b * 128 + c] = m;
}

// ---------------- final: reduce partials2 + bf16-round + FC + softmax (1 block) ----------------

__global__ __launch_bounds__(1024) void k_final(const float* __restrict__ partials2,
                                                const float* __restrict__ Wfc,
                                                const float* __restrict__ bfc,
                                                float* __restrict__ outp) {
    __shared__ float red[1024];
    int t = threadIdx.x;
    int c = t & 127;             // channel
    int slice = t >> 7;          // 8 row-slices of 64 rows each
    float m = 0.f;
    int i0 = slice * (PBLK2 / 8);
#pragma unroll
    for (int k = 0; k < PBLK2 / 8; ++k)
        m = fmaxf(m, partials2[(size_t)(i0 + k) * 128 + c]);
    red[t] = m;
    __syncthreads();
    if (t < 128) {
        float v = red[t];
#pragma unroll
        for (int s = 1; s < 8; ++s) v = fmaxf(v, red[s * 128 + t]);
        // bf16-round the pooled value (matches the prior pipeline numerics)
        red[t] = __uint_as_float((unsigned int)f2bf(v) << 16);
    }
    __syncthreads();
    if (t < 64) {
        int j = t & 7;
        int kk = t >> 3;
        float partial = 0.f;
        for (int k = kk * 16; k < kk * 16 + 16; ++k) partial += red[k] * Wfc[k * 8 + j];
        for (int o = 8; o < 64; o <<= 1) partial += __shfl_xor(partial, o);
        float logit = partial + bfc[j];
        float mxl = logit;
        for (int o = 1; o < 8; o <<= 1) mxl = fmaxf(mxl, __shfl_xor(mxl, o));
        float ex = __expf(logit - mxl);
        float sm = ex;
        for (int o = 1; o < 8; o <<= 1) sm += __shfl_xor(sm, o);
        if (t < 8) outp[t] = ex / sm;
    }
}

// ---------------- launch ----------------

extern "C" void kernel_launch(void* const* d_in, const int* in_sizes, int n_in,
                              void* d_out, int out_size, void* d_ws, size_t ws_size,
                              hipStream_t stream) {
    const float* x   = (const float*)d_in[0];
    const int*   src = (const int*)d_in[1];
    const int*   dst = (const int*)d_in[2];
    const float* W1  = (const float*)d_in[3];
    const float* al1 = (const float*)d_in[4];
    const float* ar1 = (const float*)d_in[5];
    const float* W2  = (const float*)d_in[6];
    const float* al2 = (const float*)d_in[7];
    const float* ar2 = (const float*)d_in[8];
    const float* W3  = (const float*)d_in[9];
    const float* al3 = (const float*)d_in[10];
    const float* ar3 = (const float*)d_in[11];
    const float* Wfc = (const float*)d_in[12];
    const float* bfc = (const float*)d_in[13];
    float* out = (float*)d_out;

    char* p = (char*)d_ws;
    auto alloc = [&](size_t bytes) {
        char* r = p;
        p += (bytes + 255) & ~(size_t)255;
        return r;
    };
    unsigned char* Fb_a = (unsigned char*)alloc((size_t)NN * FD);   // fp8 features
    unsigned char* Fb_b = (unsigned char*)alloc((size_t)NN * FD);
    unsigned int*  Hb   = (unsigned int*)alloc((size_t)NN * 64 * 4); // bf16x2-packed H
    float* el_a   = (float*)alloc((size_t)NN * 4 * 4);
    float* er_a   = (float*)alloc((size_t)NN * 4 * 4);
    int*   off    = (int*)alloc((size_t)NN * 4);
    int*   deg    = (int*)alloc((size_t)NN * 4);
    int*   ssrc   = (int*)alloc((size_t)NB * CAP * 4);
    unsigned int* pairs = (unsigned int*)alloc((size_t)NB * CAP * 4);
    int*   gcur   = (int*)alloc((size_t)NB * 4);
    float* partials  = (float*)alloc((size_t)AB * 128 * 4);     // 12.8 MB
    float* partials2 = (float*)alloc((size_t)PBLK2 * 128 * 4);  // 256 KB
    unsigned short* Wth = (unsigned short*)alloc(3 * 16384 * 2);
    // pairs (7.5 MB) is dead after k_sortgemm1's bsort -> overlay layer-B el/er (3.2 MB)
    float* el_b = (float*)pairs;
    float* er_b = (float*)pairs + (size_t)NN * 4;

    const int BB = (NE + CHUNK - 1) / CHUNK;  // 196

    k_wsplit<<<192, 256, 0, stream>>>(W1, W2, W3, Wth, gcur);
    k_bucket<<<BB, 256, 0, stream>>>(src, dst, gcur, pairs);

    // bsort + layer-1 GEMM fused (independent work) -> Fb_a (fp8), el_a, er_a
    k_sortgemm1<<<NB + GB, 256, 0, stream>>>(pairs, gcur, off, deg, ssrc,
                                             x, Wth, Fb_a, al1, ar1, el_a, er_a);
    // layer-1 agg -> Hb (bf16)
    k_agg8<<<AB, 256, 0, stream>>>(Fb_a, el_a, er_a, off, deg, ssrc, Hb);
    // layer-2 GEMM: Hb -> Fb_b (fp8), el_b, er_b
    k_gemm8<<<GB, 256, 0, stream>>>((const unsigned short*)Hb, Wth + 16384,
                                    Fb_b, al2, ar2, el_b, er_b);
    // layer-2 agg -> Hb
    k_agg8<<<AB, 256, 0, stream>>>(Fb_b, el_b, er_b, off, deg, ssrc, Hb);
    // layer-3 GEMM: Hb -> Fb_a (fp8), el_a, er_a
    k_gemm8<<<GB, 256, 0, stream>>>((const unsigned short*)Hb, Wth + 32768,
                                    Fb_a, al3, ar3, el_a, er_a);
    // layer-3 agg + block-local max pool
    k_aggpool8<<<AB, 256, 0, stream>>>(Fb_a, el_a, er_a, off, deg, ssrc, partials);
    k_poolred<<<PBLK2, 128, 0, stream>>>(partials, partials2);
    k_final<<<1, 1024, 0, stream>>>(partials2, Wfc, bfc, out);
}

// Round 9
// 410.749 us; speedup vs baseline: 1.5216x; 1.0425x over previous
//
#include <hip/hip_runtime.h>

#define NN 100000   // nodes
#define NE 1600000  // edges
#define FD 128      // feature dim (4 heads x 32 ch); fp8 row = 128 B
#define NB 391      // ceil(NN/256) dst-buckets
#define CAP 4800    // padded bucket capacity (mean 4096, sigma 64 -> +11 sigma)
#define CHUNK 8192  // edges per k_bucket block -> 196 blocks
#define GB 782      // gemm tiles (128 rows each)
#define AB 25000    // agg blocks (4 nodes each, 1 node per wave)
#define PBLK2 512   // second-stage pool rows

typedef __attribute__((ext_vector_type(8))) short bf16x8;
typedef __attribute__((ext_vector_type(4))) float f32x4;
typedef __attribute__((ext_vector_type(2))) float f32x2;

union B8 { bf16x8 v; unsigned int u[4]; };

// ---------------- helpers ----------------

__device__ __forceinline__ unsigned short f2bf(float x) {
    unsigned int u = __float_as_uint(x);
    u += 0x7fffu + ((u >> 16) & 1u);   // round-to-nearest-even
    return (unsigned short)(u >> 16);
}

__device__ __forceinline__ unsigned char f2fp8(float x) {
    // low byte of packed fp8 conversion (RNE, saturating)
    return (unsigned char)__builtin_amdgcn_cvt_pk_fp8_f32(x, 0.f, 0u, false);
}

__device__ __forceinline__ unsigned int pkhi(unsigned int ua, unsigned int ub) {
    return __builtin_amdgcn_perm(ub, ua, 0x07060302);
}

// pack 8 f32 -> 8 bf16 (hi 16 bits, truncation — same grid as all passing rounds)
__device__ __forceinline__ bf16x8 pack8hi(const float4& x0, const float4& x1) {
    float f[8] = {x0.x, x0.y, x0.z, x0.w, x1.x, x1.y, x1.z, x1.w};
    B8 H;
#pragma unroll
    for (int i = 0; i < 4; i++) {
        unsigned int ua = __float_as_uint(f[2 * i]);
        unsigned int ub = __float_as_uint(f[2 * i + 1]);
        H.u[i] = pkhi(ua, ub);
    }
    return H.v;
}

// ---------------- W -> bf16 + gcur zeroing (one dispatch) ----------------

__global__ void k_wsplit(const float* __restrict__ W1, const float* __restrict__ W2,
                         const float* __restrict__ W3, unsigned short* __restrict__ Wth,
                         int* __restrict__ gcur) {
    int gid = blockIdx.x * 256 + threadIdx.x;  // 0..49151
    if (gid < NB) gcur[gid] = 0;
    int w = gid >> 14;
    int tid = gid & 16383;
    const float* W = (w == 0) ? W1 : (w == 1) ? W2 : W3;
    int n = tid >> 7, k = tid & 127;
    Wth[gid] = f2bf(W[k * 128 + n]);   // RNE bf16 weights
}

// ---------------- bucket scatter into padded per-bucket slots ----------------
// pairs[b*CAP + slot] = src | (dst&255)<<17

__global__ __launch_bounds__(256) void k_bucket(const int* __restrict__ src,
                                                const int* __restrict__ dst,
                                                int* __restrict__ gcur,
                                                unsigned int* __restrict__ pairs) {
    __shared__ int scnt[NB];
    __shared__ int sbase[NB];
    int t = threadIdx.x;
    for (int i = t; i < NB; i += 256) scnt[i] = 0;
    __syncthreads();
    int e0 = blockIdx.x * CHUNK, e1 = min(e0 + CHUNK, NE);
    for (int i = e0 + t; i < e1; i += 256) atomicAdd(&scnt[dst[i] >> 8], 1);
    __syncthreads();
    for (int i = t; i < NB; i += 256) {
        int c = scnt[i];
        sbase[i] = (c > 0) ? (i * CAP + atomicAdd(&gcur[i], c)) : 0;
        scnt[i] = 0;  // reuse as local cursor
    }
    __syncthreads();
    for (int i = e0 + t; i < e1; i += 256) {
        int d = dst[i];
        int b = d >> 8;
        int r = atomicAdd(&scnt[b], 1);
        pairs[sbase[b] + r] = (unsigned int)src[i] | ((unsigned int)(d & 255) << 17);
    }
}

// ---------------- per-bucket counting sort body ----------------

__device__ void bsort_body(int b, const unsigned int* __restrict__ pairs,
                           const int* __restrict__ gcur, int* __restrict__ off,
                           int* __restrict__ deg, int* __restrict__ ssrc) {
    __shared__ int hcnt[256];
    __shared__ int cur[256];
    int t = threadIdx.x;
    int cnt = gcur[b];
    int estart = b * CAP;
    hcnt[t] = 0;
    __syncthreads();
    for (int i = t; i < cnt; i += 256)
        atomicAdd(&hcnt[(pairs[estart + i] >> 17) & 255], 1);
    __syncthreads();
    int v = hcnt[t];
    cur[t] = v;
    __syncthreads();
    for (int o = 1; o < 256; o <<= 1) {
        int x = (t >= o) ? cur[t - o] : 0;
        __syncthreads();
        cur[t] += x;
        __syncthreads();
    }
    int excl = cur[t] - v;
    int node = (b << 8) + t;
    if (node < NN) {
        off[node] = estart + excl;
        deg[node] = v;
    }
    __syncthreads();
    cur[t] = estart + excl;
    __syncthreads();
    for (int i = t; i < cnt; i += 256) {
        unsigned int p = pairs[estart + i];
        int pos = atomicAdd(&cur[(p >> 17) & 255], 1);
        ssrc[pos] = (int)(p & 0x1ffffu);
    }
}

// ---------------- fused GEMM epilogue (2 row-groups): fp8 features + el/er ----------------
// Features staged as fp8 bytes in wave-private LDS, then copied out as uint4
// (coalesced) — avoids 1-byte scattered global stores (partial-line RMW).

__device__ __forceinline__ void epilogue(f32x4 acc[2][8], int row0, int q, int r, int nrows,
                                         const float* __restrict__ al,
                                         const float* __restrict__ ar,
                                         unsigned char* __restrict__ FbG,
                                         float* __restrict__ el, float* __restrict__ er,
                                         unsigned char* __restrict__ sg8, int lane) {
#pragma unroll
    for (int g = 0; g < 2; g++) {
#pragma unroll
        for (int i = 0; i < 4; i++) {
            int row_l = g * 16 + q * 4 + i;
            int row = row0 + row_l;
            float elp[4], erp[4];
#pragma unroll
            for (int h = 0; h < 4; h++) { elp[h] = 0.f; erp[h] = 0.f; }
#pragma unroll
            for (int nt = 0; nt < 8; nt++) {
                int h = nt >> 1;
                int c = ((nt & 1) << 4) + r;
                float v = acc[g][nt][i];
                elp[h] = fmaf(v, al[h * 32 + c], elp[h]);
                erp[h] = fmaf(v, ar[h * 32 + c], erp[h]);
            }
#pragma unroll
            for (int o = 1; o < 16; o <<= 1) {
#pragma unroll
                for (int h = 0; h < 4; h++) {
                    elp[h] += __shfl_xor(elp[h], o);
                    erp[h] += __shfl_xor(erp[h], o);
                }
            }
#pragma unroll
            for (int nt = 0; nt < 8; nt++)
                sg8[row_l * 128 + nt * 16 + r] = f2fp8(acc[g][nt][i]);
            if (row < nrows) {
                int hh = r & 3;
                float ve = (hh & 2) ? ((hh & 1) ? elp[3] : elp[2]) : ((hh & 1) ? elp[1] : elp[0]);
                float vr = (hh & 2) ? ((hh & 1) ? erp[3] : erp[2]) : ((hh & 1) ? erp[1] : erp[0]);
                if (r < 4) el[row * 4 + hh] = ve;
                else if (r < 8) er[row * 4 + hh] = vr;
            }
        }
    }
    // copy out the wave's 32 rows (4 KB), wave-private -> no barrier needed
#pragma unroll
    for (int it = 0; it < 4; it++) {
        int off = it * 1024 + lane * 16;
        int row = row0 + (off >> 7);
        uint4 v = *(const uint4*)(sg8 + off);
        if (row < nrows) *(uint4*)(FbG + (size_t)row * FD + (off & 127)) = v;
    }
}

// ---------------- GEMM body (layer 1): A f32 -> bf16, single MFMA per tile ----------------

__device__ void gemm_f32_body(int bid, const float* __restrict__ A,
                              const unsigned short* __restrict__ Wth,
                              unsigned char* __restrict__ Fb, int nrows,
                              const float* __restrict__ al, const float* __restrict__ ar,
                              float* __restrict__ el, float* __restrict__ er) {
    __shared__ unsigned char sg8[4][4096];   // per-wave fp8 staging (32 rows x 128 B)
    int t = threadIdx.x;
    int wave = t >> 6, lane = t & 63;
    int r = lane & 15, q = lane >> 4;
    int row0 = bid * 128 + wave * 32;
    int rg0 = row0 + r, rg1 = row0 + 16 + r;

    f32x4 acc[2][8];
#pragma unroll
    for (int g = 0; g < 2; g++)
#pragma unroll
        for (int nt = 0; nt < 8; nt++) acc[g][nt] = (f32x4){0.f, 0.f, 0.f, 0.f};

#pragma unroll
    for (int ks = 0; ks < 4; ks++) {
        int k0 = ks * 32 + q * 8;
        float4 z = make_float4(0.f, 0.f, 0.f, 0.f);
        float4 a0 = z, a1 = z, b0 = z, b1 = z;
        if (rg0 < nrows) {
            const float* pa = A + (size_t)rg0 * FD + k0;
            a0 = *(const float4*)pa;
            a1 = *(const float4*)(pa + 4);
        }
        if (rg1 < nrows) {
            const float* pb = A + (size_t)rg1 * FD + k0;
            b0 = *(const float4*)pb;
            b1 = *(const float4*)(pb + 4);
        }
        bf16x8 ah0 = pack8hi(a0, a1);
        bf16x8 ah1 = pack8hi(b0, b1);
#pragma unroll
        for (int nt = 0; nt < 8; nt++) {
            int wo = ((nt * 16 + r) << 7) + k0;
            bf16x8 bh = *(const bf16x8*)(Wth + wo);
            acc[0][nt] = __builtin_amdgcn_mfma_f32_16x16x32_bf16(ah0, bh, acc[0][nt], 0, 0, 0);
            acc[1][nt] = __builtin_amdgcn_mfma_f32_16x16x32_bf16(ah1, bh, acc[1][nt], 0, 0, 0);
        }
    }
    epilogue(acc, row0, q, r, nrows, al, ar, Fb, el, er, sg8[wave], lane);
}

// ---------------- fused dispatch: bsort (blocks 0..NB-1) + layer-1 GEMM (rest) ----------------

__global__ __launch_bounds__(256) void k_sortgemm1(const unsigned int* __restrict__ pairs,
                                                   const int* __restrict__ gcur,
                                                   int* __restrict__ off, int* __restrict__ deg,
                                                   int* __restrict__ ssrc,
                                                   const float* __restrict__ A,
                                                   const unsigned short* __restrict__ Wth,
                                                   unsigned char* __restrict__ Fb,
                                                   const float* __restrict__ al,
                                                   const float* __restrict__ ar,
                                                   float* __restrict__ el,
                                                   float* __restrict__ er) {
    int b = blockIdx.x;
    if (b < NB) bsort_body(b, pairs, gcur, off, deg, ssrc);
    else gemm_f32_body(b - NB, A, Wth, Fb, NN, al, ar, el, er);
}

// ---------------- wave-wide aggregation of one dst node (relu'd output) ----------------
// Features gathered as fp8 (8 B/lane), dequant via v_cvt_pk_f32_fp8, accumulated
// as f32x2 pairs (v_pk_fma_f32 path). Batch loop software-pipelined: next batch's
// sid/el prefetched during the current batch's FMA block; all 4 row loads issued
// before any cvt/fma (4 loads in flight per lane).
// Result: acc8[z] = relu(H[d][8*(lane&15)+z]), replicated across 4 lane-groups.

__device__ __forceinline__ void agg_node(int d,
        const unsigned char* __restrict__ Fb,
        const float* __restrict__ el, const float* __restrict__ er,
        const int* __restrict__ off, const int* __restrict__ deg_,
        const int* __restrict__ ssrc, int lane, float acc8[8]) {
    f32x2 acc2[4];
#pragma unroll
    for (int z = 0; z < 4; z++) acc2[z] = (f32x2){0.f, 0.f};
    int start = off[d];
    int dg = deg_[d];
    if (dg > 0) {
        int h = lane & 3;
        int eloc = lane >> 2;
        int g = lane >> 4;
        int c16 = lane & 15;
        int hsel2 = c16 >> 2;
        float er_h = er[d * 4 + h];
        float s = 0.f;
        // prefetch batch 0's edge data
        bool valid = (eloc < dg);
        int sid = valid ? ssrc[start + eloc] : 0;
        float elv = el[sid * 4 + h];        // sid=0 fallback: valid row, a=0 below
        for (int base = 0; base < dg; base += 16) {
            // alpha for the current batch (inputs prefetched last iteration)
            float v = elv + er_h;
            float e = fmaxf(v, 0.2f * v);   // leaky_relu, exact
            float a = valid ? __expf(e) : 0.f;
            int sidc = sid;
            // prefetch next batch's edge data (latency hides under FMA block)
            int i2 = base + 16 + eloc;
            valid = (i2 < dg);
            sid = valid ? ssrc[start + i2] : 0;
            elv = el[sid * 4 + h];
            s += a;
            // broadcast sids/alphas; issue all 4 feature loads up front
            uint2 u[4];
            float av[4];
#pragma unroll
            for (int k = 0; k < 4; k++) {
                int sl = 16 * k + 4 * g;               // lane holding sid of row 4k+g
                int sv = __shfl(sidc, sl, 64);
                av[k] = __shfl(a, sl + hsel2, 64);     // alpha for my head
                u[k] = *(const uint2*)(Fb + (size_t)sv * FD + c16 * 8);
            }
#pragma unroll
            for (int k = 0; k < 4; k++) {
                f32x2 av2 = {av[k], av[k]};
                f32x2 p0 = __builtin_amdgcn_cvt_pk_f32_fp8(u[k].x, false);
                f32x2 p1 = __builtin_amdgcn_cvt_pk_f32_fp8(u[k].x, true);
                f32x2 p2 = __builtin_amdgcn_cvt_pk_f32_fp8(u[k].y, false);
                f32x2 p3 = __builtin_amdgcn_cvt_pk_f32_fp8(u[k].y, true);
                acc2[0] = __builtin_elementwise_fma(p0, av2, acc2[0]);
                acc2[1] = __builtin_elementwise_fma(p1, av2, acc2[1]);
                acc2[2] = __builtin_elementwise_fma(p2, av2, acc2[2]);
                acc2[3] = __builtin_elementwise_fma(p3, av2, acc2[3]);
            }
        }
        float* accf = (float*)acc2;
        // merge the 4 row-groups (results become replicated wave-wide)
#pragma unroll
        for (int z = 0; z < 8; z++) {
            accf[z] += __shfl_xor(accf[z], 16, 64);
            accf[z] += __shfl_xor(accf[z], 32, 64);
        }
        for (int o = 4; o < 64; o <<= 1) s += __shfl_xor(s, o, 64);
        float inv = 1.f / __shfl(s, hsel2, 64);
#pragma unroll
        for (int z = 0; z < 8; z++) accf[z] *= inv;
    }
    float* accf = (float*)acc2;
#pragma unroll
    for (int z = 0; z < 8; z++) acc8[z] = fmaxf(accf[z], 0.f);   // relu (all 3 layers)
}

// ---------------- standalone agg: 4 waves/block, 1 node/wave, bf16 Hb out ----------------

__global__ __launch_bounds__(256) void k_agg8(
        const unsigned char* __restrict__ Fb,
        const float* __restrict__ el, const float* __restrict__ er,
        const int* __restrict__ off, const int* __restrict__ deg_,
        const int* __restrict__ ssrc,
        unsigned int* __restrict__ Hb) {
    int wave = threadIdx.x >> 6, lane = threadIdx.x & 63;
    int d = blockIdx.x * 4 + wave;
    if (d >= NN) return;
    float acc8[8];
    agg_node(d, Fb, el, er, off, deg_, ssrc, lane, acc8);
    int c16 = lane & 15, g = lane >> 4;
    if (g == 0) {   // 16 lanes write the packed bf16 row (256 B contiguous)
        uint4 pk;
        pk.x = ((unsigned int)f2bf(acc8[1]) << 16) | f2bf(acc8[0]);
        pk.y = ((unsigned int)f2bf(acc8[3]) << 16) | f2bf(acc8[2]);
        pk.z = ((unsigned int)f2bf(acc8[5]) << 16) | f2bf(acc8[4]);
        pk.w = ((unsigned int)f2bf(acc8[7]) << 16) | f2bf(acc8[6]);
        *(uint4*)(Hb + (size_t)d * 64 + c16 * 4) = pk;
    }
}

// ---------------- GEMM (layers 2,3): A bf16 (Hb), single MFMA, fp8 out ----------------

__global__ __launch_bounds__(256) void k_gemm8(const unsigned short* __restrict__ A,
                                               const unsigned short* __restrict__ Wth,
                                               unsigned char* __restrict__ Fb,
                                               const float* __restrict__ al,
                                               const float* __restrict__ ar,
                                               float* __restrict__ el,
                                               float* __restrict__ er) {
    __shared__ unsigned char sg8[4][4096];   // per-wave fp8 staging (32 rows x 128 B)
    int t = threadIdx.x;
    int wave = t >> 6, lane = t & 63;
    int r = lane & 15, q = lane >> 4;
    int row0 = blockIdx.x * 128 + wave * 32;
    int rg0 = row0 + r, rg1 = row0 + 16 + r;

    f32x4 acc[2][8];
#pragma unroll
    for (int g = 0; g < 2; g++)
#pragma unroll
        for (int nt = 0; nt < 8; nt++) acc[g][nt] = (f32x4){0.f, 0.f, 0.f, 0.f};

#pragma unroll
    for (int ks = 0; ks < 4; ks++) {
        int k0 = ks * 32 + q * 8;
        bf16x8 a0 = {0, 0, 0, 0, 0, 0, 0, 0};
        bf16x8 a1 = {0, 0, 0, 0, 0, 0, 0, 0};
        if (rg0 < NN) a0 = *(const bf16x8*)(A + (size_t)rg0 * FD + k0);
        if (rg1 < NN) a1 = *(const bf16x8*)(A + (size_t)rg1 * FD + k0);
#pragma unroll
        for (int nt = 0; nt < 8; nt++) {
            int wo = ((nt * 16 + r) << 7) + k0;
            bf16x8 bh = *(const bf16x8*)(Wth + wo);
            acc[0][nt] = __builtin_amdgcn_mfma_f32_16x16x32_bf16(a0, bh, acc[0][nt], 0, 0, 0);
            acc[1][nt] = __builtin_amdgcn_mfma_f32_16x16x32_bf16(a1, bh, acc[1][nt], 0, 0, 0);
        }
    }
    epilogue(acc, row0, q, r, NN, al, ar, Fb, el, er, sg8[wave], lane);
}

// ---------------- fused agg (layer 3) + block-local max pool (4-wave barrier) ----------------

__global__ __launch_bounds__(256) void k_aggpool8(
        const unsigned char* __restrict__ Fb,
        const float* __restrict__ el, const float* __restrict__ er,
        const int* __restrict__ off, const int* __restrict__ deg_,
        const int* __restrict__ ssrc,
        float* __restrict__ partials) {
    __shared__ float wmax[4][128];
    int t = threadIdx.x;
    int wave = t >> 6, lane = t & 63;
    int c16 = lane & 15, g = lane >> 4;
    int d = blockIdx.x * 4 + wave;
    float acc8[8];
    if (d < NN) {
        agg_node(d, Fb, el, er, off, deg_, ssrc, lane, acc8);
    } else {
#pragma unroll
        for (int z = 0; z < 8; z++) acc8[z] = 0.f;
    }
    if (g == 0) {
#pragma unroll
        for (int z = 0; z < 8; z++) wmax[wave][c16 * 8 + z] = acc8[z];
    }
    __syncthreads();
    if (t < 128) {
        float m = fmaxf(fmaxf(wmax[0][t], wmax[1][t]), fmaxf(wmax[2][t], wmax[3][t]));
        partials[(size_t)blockIdx.x * 128 + t] = m;
    }
}

// ---------------- pool reduce: AB partial rows -> PBLK2 rows (contiguous chunks) ----------------

__global__ __launch_bounds__(128) void k_poolred(const float* __restrict__ partials,
                                                 float* __restrict__ partials2) {
    int c = threadIdx.x;         // channel 0..127
    int b = blockIdx.x;          // 0..PBLK2-1
    const int R = (AB + PBLK2 - 1) / PBLK2;   // 49
    int r0 = b * R, r1 = min(AB, r0 + R);
    float m = 0.f;
    for (int r = r0; r < r1; ++r)
        m = fmaxf(m, partials[(size_t)r * 128 + c]);
    partials2[(size_t)b * 128 + c] = m;
}

// ---------------- final: reduce partials2 + bf16-round + FC + softmax (1 block) ----------------

__global__ __launch_bounds__(1024) void k_final(const float* __restrict__ partials2,
                                                const float* __restrict__ Wfc,
                                                const float* __restrict__ bfc,
                                                float* __restrict__ outp) {
    __shared__ float red[1024];
    int t = threadIdx.x;
    int c = t & 127;             // channel
    int slice = t >> 7;          // 8 row-slices of 64 rows each
    float m = 0.f;
    int i0 = slice * (PBLK2 / 8);
#pragma unroll
    for (int k = 0; k < PBLK2 / 8; ++k)
        m = fmaxf(m, partials2[(size_t)(i0 + k) * 128 + c]);
    red[t] = m;
    __syncthreads();
    if (t < 128) {
        float v = red[t];
#pragma unroll
        for (int s = 1; s < 8; ++s) v = fmaxf(v, red[s * 128 + t]);
        // bf16-round the pooled value (matches the prior pipeline numerics)
        red[t] = __uint_as_float((unsigned int)f2bf(v) << 16);
    }
    __syncthreads();
    if (t < 64) {
        int j = t & 7;
        int kk = t >> 3;
        float partial = 0.f;
        for (int k = kk * 16; k < kk * 16 + 16; ++k) partial += red[k] * Wfc[k * 8 + j];
        for (int o = 8; o < 64; o <<= 1) partial += __shfl_xor(partial, o);
        float logit = partial + bfc[j];
        float mxl = logit;
        for (int o = 1; o < 8; o <<= 1) mxl = fmaxf(mxl, __shfl_xor(mxl, o));
        float ex = __expf(logit - mxl);
        float sm = ex;
        for (int o = 1; o < 8; o <<= 1) sm += __shfl_xor(sm, o);
        if (t < 8) outp[t] = ex / sm;
    }
}

// ---------------- launch ----------------

extern "C" void kernel_launch(void* const* d_in, const int* in_sizes, int n_in,
                              void* d_out, int out_size, void* d_ws, size_t ws_size,
                              hipStream_t stream) {
    const float* x   = (const float*)d_in[0];
    const int*   src = (const int*)d_in[1];
    const int*   dst = (const int*)d_in[2];
    const float* W1  = (const float*)d_in[3];
    const float* al1 = (const float*)d_in[4];
    const float* ar1 = (const float*)d_in[5];
    const float* W2  = (const float*)d_in[6];
    const float* al2 = (const float*)d_in[7];
    const float* ar2 = (const float*)d_in[8];
    const float* W3  = (const float*)d_in[9];
    const float* al3 = (const float*)d_in[10];
    const float* ar3 = (const float*)d_in[11];
    const float* Wfc = (const float*)d_in[12];
    const float* bfc = (const float*)d_in[13];
    float* out = (float*)d_out;

    char* p = (char*)d_ws;
    auto alloc = [&](size_t bytes) {
        char* r = p;
        p += (bytes + 255) & ~(size_t)255;
        return r;
    };
    unsigned char* Fb_a = (unsigned char*)alloc((size_t)NN * FD);   // fp8 features
    unsigned char* Fb_b = (unsigned char*)alloc((size_t)NN * FD);
    unsigned int*  Hb   = (unsigned int*)alloc((size_t)NN * 64 * 4); // bf16x2-packed H
    float* el_a   = (float*)alloc((size_t)NN * 4 * 4);
    float* er_a   = (float*)alloc((size_t)NN * 4 * 4);
    int*   off    = (int*)alloc((size_t)NN * 4);
    int*   deg    = (int*)alloc((size_t)NN * 4);
    int*   ssrc   = (int*)alloc((size_t)NB * CAP * 4);
    unsigned int* pairs = (unsigned int*)alloc((size_t)NB * CAP * 4);
    int*   gcur   = (int*)alloc((size_t)NB * 4);
    float* partials  = (float*)alloc((size_t)AB * 128 * 4);     // 12.8 MB
    float* partials2 = (float*)alloc((size_t)PBLK2 * 128 * 4);  // 256 KB
    unsigned short* Wth = (unsigned short*)alloc(3 * 16384 * 2);
    // pairs (7.5 MB) is dead after k_sortgemm1's bsort -> overlay layer-B el/er (3.2 MB)
    float* el_b = (float*)pairs;
    float* er_b = (float*)pairs + (size_t)NN * 4;

    const int BB = (NE + CHUNK - 1) / CHUNK;  // 196

    k_wsplit<<<192, 256, 0, stream>>>(W1, W2, W3, Wth, gcur);
    k_bucket<<<BB, 256, 0, stream>>>(src, dst, gcur, pairs);

    // bsort + layer-1 GEMM fused (independent work) -> Fb_a (fp8), el_a, er_a
    k_sortgemm1<<<NB + GB, 256, 0, stream>>>(pairs, gcur, off, deg, ssrc,
                                             x, Wth, Fb_a, al1, ar1, el_a, er_a);
    // layer-1 agg -> Hb (bf16)
    k_agg8<<<AB, 256, 0, stream>>>(Fb_a, el_a, er_a, off, deg, ssrc, Hb);
    // layer-2 GEMM: Hb -> Fb_b (fp8), el_b, er_b
    k_gemm8<<<GB, 256, 0, stream>>>((const unsigned short*)Hb, Wth + 16384,
                                    Fb_b, al2, ar2, el_b, er_b);
    // layer-2 agg -> Hb
    k_agg8<<<AB, 256, 0, stream>>>(Fb_b, el_b, er_b, off, deg, ssrc, Hb);
    // layer-3 GEMM: Hb -> Fb_a (fp8), el_a, er_a
    k_gemm8<<<GB, 256, 0, stream>>>((const unsigned short*)Hb, Wth + 32768,
                                    Fb_a, al3, ar3, el_a, er_a);
    // layer-3 agg + block-local max pool
    k_aggpool8<<<AB, 256, 0, stream>>>(Fb_a, el_a, er_a, off, deg, ssrc, partials);
    k_poolred<<<PBLK2, 128, 0, stream>>>(partials, partials2);
    k_final<<<1, 1024, 0, stream>>>(partials2, Wfc, bfc, out);
}